// Round 1
// 816.584 us; speedup vs baseline: 1.1153x; 1.1153x over previous
//
#include <hip/hip_runtime.h>
#include <hip/hip_bf16.h>
#include <cstdint>
#include <cstddef>

// FocusedLinearAttention on MI355X (gfx950).
// R3: GEMMs rewritten to the 256x256 8-phase template (T1 XCD swizzle +
// T2 LDS XOR-swizzle + T3/T4 phase-split with counted vmcnt + T5 setprio).
// 512 thr / 8 waves, BK=64, 128KiB LDS double-buffer, raw s_barrier,
// vmcnt(4) once per K-tile (never drained to 0 in the loop).

typedef __bf16 bf16;
typedef __bf16 bf16x4 __attribute__((ext_vector_type(4)));
typedef __bf16 bf16x8 __attribute__((ext_vector_type(8)));
typedef float f32x4 __attribute__((ext_vector_type(4)));
typedef float f32x2 __attribute__((ext_vector_type(2)));

#define NB 8
#define NSEQ 4096
#define NC 1024
#define NH 16
#define ND 64
#define NBH 128      // NB*NH
#define NM 32768     // NB*NSEQ
#define EPSF 1e-6f
#define KSPLIT 8

__device__ __forceinline__ void async16(const void* g, void* l) {
  __builtin_amdgcn_global_load_lds(
      (const __attribute__((address_space(1))) void*)g,
      (__attribute__((address_space(3))) void*)l, 16, 0, 0);
}

__device__ __forceinline__ unsigned pack_bf16(float a, float b) {
  union { bf16 h[2]; unsigned u; } t;
  t.h[0] = (bf16)a; t.h[1] = (bf16)b;
  return t.u;
}

#define BAR() asm volatile("s_barrier" ::: "memory")
#define WAIT_LGKM(N) asm volatile("s_waitcnt lgkmcnt(" #N ")" ::: "memory")
#define WAIT_VM(N) asm volatile("s_waitcnt vmcnt(" #N ")" ::: "memory")
#define SCHEDB() __builtin_amdgcn_sched_barrier(0)

// ---------------- fp32 -> bf16 convert ----------------
__global__ __launch_bounds__(256) void cvt_bf16(const float* __restrict__ src,
                                                bf16* __restrict__ dst, int n4) {
  int i = blockIdx.x * 256 + threadIdx.x;
  if (i < n4) {
    f32x4 v = ((const f32x4*)src)[i];
    bf16x4 o;
    o[0] = (bf16)v[0]; o[1] = (bf16)v[1]; o[2] = (bf16)v[2]; o[3] = (bf16)v[3];
    ((bf16x4*)dst)[i] = o;
  }
}

// ---------------- inv softplus(scale) ----------------
__global__ __launch_bounds__(256) void prep_scale(const float* __restrict__ scale,
                                                  float* __restrict__ inv_sc) {
  int c = blockIdx.x * 256 + threadIdx.x;
  if (c < NC) inv_sc[c] = 1.0f / log1pf(expf(scale[c]));
}

// ---------------- 256x256 bf16 MFMA GEMM, C = A @ B^T, 8-phase ----------------
// A: (M x K) bf16 row-major, Bm: (N x K) bf16 row-major. K % 64 == 0, M,N % 256 == 0.
// MODE 0: qkv. col < 2048 -> bf16 outqk (width 2048); col >= 2048 -> bf16 outv (1024)
// MODE 1: fp32 out width 1024, += bias
template <int MODE>
__global__ __launch_bounds__(512, 2) void gemm_bt8(const bf16* __restrict__ A,
                                                   const bf16* __restrict__ Bm, int K,
                                                   bf16* __restrict__ outqk,
                                                   bf16* __restrict__ outv,
                                                   float* __restrict__ outf,
                                                   const float* __restrict__ bias) {
  // 2 buffers x (256 rows x 64 cols) bf16 each for A and B = 128 KiB total
  __shared__ bf16 As[2 * 16384];
  __shared__ bf16 Bs[2 * 16384];

  const int tid = threadIdx.x;
  const int w = tid >> 6, lane = tid & 63;
  const int q4 = lane >> 4, l16 = lane & 15;
  const int l7 = l16 & 7;
  const int wm = (w >> 2) * 128, wn = (w & 3) * 64;   // wave -> 128x64 of C

  // T1: bijective XCD swizzle (nwg % 8 == 0 for all launches here)
  const int gx = gridDim.x;
  const int nwg = gx * gridDim.y;
  const int bid0 = blockIdx.y * gx + blockIdx.x;
  const int cpx = nwg >> 3;
  const int bid = (bid0 & 7) * cpx + (bid0 >> 3);
  const long row0 = (long)(bid / gx) * 256;
  const long col0 = (long)(bid % gx) * 256;

  // Staging geometry: slot s = w*128 + t2*64 + lane; LDS dest linear (slot*16B).
  // T2 swizzle applied on the GLOBAL SOURCE (rule 21): slot (r = s>>3, j = s&7)
  // holds global (row r, colgroup j ^ (r&7)).  Involution; reads use same XOR.
  const int s0 = w * 128 + lane;                 // t2=0 slot (t2=1: +64)
  const int ra = s0 >> 3;                        // row within half-tile
  const int cg = ((s0 & 7) ^ (ra & 7)) << 3;     // source col element offset
  const int dl = s0 << 3;                        // LDS element offset within half

  const bf16* Abase = A + (row0 + ra) * (long)K + cg;
  const bf16* Bbase = Bm + (col0 + ra) * (long)K + cg;
  const long rstep = 8 * (long)K;                // +8 rows
  const long hstep = 128 * (long)K;              // +1 half-tile

  auto stA = [&](int buf, int h, int k0) {
    const bf16* g = Abase + h * hstep + k0;
    bf16* l = As + buf * 16384 + h * 8192 + dl;
    async16(g, l);
    async16(g + rstep, l + 512);
  };
  auto stB = [&](int buf, int h, int k0) {
    const bf16* g = Bbase + h * hstep + k0;
    bf16* l = Bs + buf * 16384 + h * 8192 + dl;
    async16(g, l);
    async16(g + rstep, l + 512);
  };

  const int nkt = K >> 6;

  // Prologue: K-tile0 (buf0) fully, K-tile1 B halves (buf1). Order matters
  // for the in-order vmcnt retirement: tile0's 8 loads are oldest.
  stA(0, 0, 0); stA(0, 1, 0);
  stB(0, 0, 0); stB(0, 1, 0);
  {
    const int k1p = (nkt > 1 ? 1 : 0) << 6;
    stB(1, 0, k1p); stB(1, 1, k1p);
  }
  WAIT_VM(4);   // K-tile0 resident; tile1 B stays in flight
  BAR();

  f32x4 acc[8][4] = {};
  bf16x8 af[4][2], bfr[4][2];

  for (int t = 0; t < nkt; ++t) {
    const int p = t & 1, q = p ^ 1;
    const int pb = p * 16384;
    const int k1 = (t + 1 < nkt ? t + 1 : nkt - 1) << 6;
    const int k2 = (t + 2 < nkt ? t + 2 : nkt - 1) << 6;

    // ---- P1: ld A(mhalf0) + B(ni0-1); stage A-h0(t+1)->buf q ----
#pragma unroll
    for (int mi = 0; mi < 4; mi++) {
      const int rb = (wm + mi * 16 + l16) * 64;
#pragma unroll
      for (int ks = 0; ks < 2; ks++)
        af[mi][ks] = *(const bf16x8*)&As[pb + rb + (((ks * 4 + q4) ^ l7) << 3)];
    }
#pragma unroll
    for (int ni = 0; ni < 2; ni++) {
      const int rb = (wn + ni * 16 + l16) * 64;
#pragma unroll
      for (int ks = 0; ks < 2; ks++)
        bfr[ni][ks] = *(const bf16x8*)&Bs[pb + rb + (((ks * 4 + q4) ^ l7) << 3)];
    }
    stA(q, 0, k1);
    WAIT_LGKM(8);
    BAR();
    WAIT_LGKM(0); SCHEDB();
    __builtin_amdgcn_s_setprio(1);
#pragma unroll
    for (int mi = 0; mi < 4; mi++)
#pragma unroll
      for (int ni = 0; ni < 2; ni++)
#pragma unroll
        for (int ks = 0; ks < 2; ks++)
          acc[mi][ni] = __builtin_amdgcn_mfma_f32_16x16x32_bf16(
              af[mi][ks], bfr[ni][ks], acc[mi][ni], 0, 0, 0);
    __builtin_amdgcn_s_setprio(0);
    BAR();

    // ---- P2: ld B(ni2-3); stage A-h1(t+1)->buf q ----
#pragma unroll
    for (int ni = 2; ni < 4; ni++) {
      const int rb = (wn + ni * 16 + l16) * 64;
#pragma unroll
      for (int ks = 0; ks < 2; ks++)
        bfr[ni][ks] = *(const bf16x8*)&Bs[pb + rb + (((ks * 4 + q4) ^ l7) << 3)];
    }
    stA(q, 1, k1);
    BAR();
    WAIT_LGKM(0); SCHEDB();
    __builtin_amdgcn_s_setprio(1);
#pragma unroll
    for (int mi = 0; mi < 4; mi++)
#pragma unroll
      for (int ni = 2; ni < 4; ni++)
#pragma unroll
        for (int ks = 0; ks < 2; ks++)
          acc[mi][ni] = __builtin_amdgcn_mfma_f32_16x16x32_bf16(
              af[mi][ks], bfr[ni][ks], acc[mi][ni], 0, 0, 0);
    __builtin_amdgcn_s_setprio(0);
    BAR();

    // ---- P3: ld A(mhalf1); stage B-h0(t+2)->buf p (B reads of p done @P2) ----
#pragma unroll
    for (int mi = 0; mi < 4; mi++) {
      const int rb = (wm + 64 + mi * 16 + l16) * 64;
#pragma unroll
      for (int ks = 0; ks < 2; ks++)
        af[mi][ks] = *(const bf16x8*)&As[pb + rb + (((ks * 4 + q4) ^ l7) << 3)];
    }
    stB(p, 0, k2);
    BAR();
    WAIT_LGKM(0); SCHEDB();
    __builtin_amdgcn_s_setprio(1);
#pragma unroll
    for (int mi = 0; mi < 4; mi++)
#pragma unroll
      for (int ni = 0; ni < 2; ni++)
#pragma unroll
        for (int ks = 0; ks < 2; ks++)
          acc[4 + mi][ni] = __builtin_amdgcn_mfma_f32_16x16x32_bf16(
              af[mi][ks], bfr[ni][ks], acc[4 + mi][ni], 0, 0, 0);
    __builtin_amdgcn_s_setprio(0);
    BAR();

    // ---- P4: stage B-h1(t+2)->buf p; MFMA from regs; counted vmcnt ----
    stB(p, 1, k2);
    BAR();
    __builtin_amdgcn_s_setprio(1);
#pragma unroll
    for (int mi = 0; mi < 4; mi++)
#pragma unroll
      for (int ni = 2; ni < 4; ni++)
#pragma unroll
        for (int ks = 0; ks < 2; ks++)
          acc[4 + mi][ni] = __builtin_amdgcn_mfma_f32_16x16x32_bf16(
              af[mi][ks], bfr[ni][ks], acc[4 + mi][ni], 0, 0, 0);
    __builtin_amdgcn_s_setprio(0);
    WAIT_VM(4);   // all of K-tile t+1 resident; only B(t+2) (4 loads) in flight
    BAR();
  }
  WAIT_VM(0);     // drain trailing stages before epilogue/exit

  // ---- packed-pair epilogue (same mapping as verified R2) ----
  const int ev = (l16 & 1) == 0;
#pragma unroll
  for (int mi = 0; mi < 8; mi++) {
    long gr0 = row0 + wm + mi * 16 + q4 * 4;
#pragma unroll
    for (int ni = 0; ni < 4; ni++) {
      long gc = col0 + wn + ni * 16 + l16;
      long cb = gc & ~1L;
      long r2 = gr0 + (ev ? 0 : 2);
      if (MODE == 0) {
        unsigned m01 = pack_bf16(acc[mi][ni][0], acc[mi][ni][1]);
        unsigned m23 = pack_bf16(acc[mi][ni][2], acc[mi][ni][3]);
        unsigned p01 = __shfl_xor(m01, 1);
        unsigned p23 = __shfl_xor(m23, 1);
        unsigned xs = ev ? m01 : p23;
        unsigned ys = ev ? p01 : m23;
        unsigned da = (xs & 0xFFFFu) | (ys << 16);
        unsigned db = (xs >> 16) | (ys & 0xFFFF0000u);
        if (col0 < 2048) {
          *(unsigned*)(outqk + r2 * 2048 + cb) = da;
          *(unsigned*)(outqk + (r2 + 1) * 2048 + cb) = db;
        } else {
          *(unsigned*)(outv + r2 * 1024 + (cb - 2048)) = da;
          *(unsigned*)(outv + (r2 + 1) * 1024 + (cb - 2048)) = db;
        }
      } else {
        float bsum = bias[gc];
        float v0 = acc[mi][ni][0] + bsum, v1 = acc[mi][ni][1] + bsum;
        float v2 = acc[mi][ni][2] + bsum, v3 = acc[mi][ni][3] + bsum;
        float p0 = __shfl_xor(v0, 1), p1 = __shfl_xor(v1, 1);
        float p2 = __shfl_xor(v2, 1), p3 = __shfl_xor(v3, 1);
        f32x2 sa, sb;
        sa[0] = ev ? v0 : p2; sa[1] = ev ? p0 : v2;
        sb[0] = ev ? v1 : p3; sb[1] = ev ? p1 : v3;
        *(f32x2*)(outf + r2 * 1024 + cb) = sa;
        *(f32x2*)(outf + (r2 + 1) * 1024 + cb) = sb;
      }
    }
  }
}

// ---------------- q/k nonlinear transform (per row over C=1024) ----------------
__global__ __launch_bounds__(256) void transform_qk(const bf16* __restrict__ qkb,
                                                    const bf16* __restrict__ peb,
                                                    const float* __restrict__ inv_sc,
                                                    bf16* __restrict__ qp,
                                                    bf16* __restrict__ kp) {
  __shared__ f32x4 red[4];
  const long row = blockIdx.x;          // 0..NM-1
  const int n = (int)(row & (NSEQ - 1));
  const int c0 = threadIdx.x * 4;

  bf16x4 qb = *(const bf16x4*)(qkb + row * 2048 + c0);
  bf16x4 kb = *(const bf16x4*)(qkb + row * 2048 + 1024 + c0);
  bf16x4 pe = *(const bf16x4*)(peb + (long)n * 1024 + c0);
  f32x4 isc = *(const f32x4*)(inv_sc + c0);

  f32x4 q3, k3;
  float s2q = 0, s6q = 0, s2k = 0, s6k = 0;
#pragma unroll
  for (int j = 0; j < 4; j++) {
    float qv = (fmaxf((float)qb[j], 0.f) + EPSF) * isc[j];
    float kv = (fmaxf((float)kb[j] + (float)pe[j], 0.f) + EPSF) * isc[j];
    float q3v = qv * qv * qv, k3v = kv * kv * kv;
    q3[j] = q3v; k3[j] = k3v;
    s2q += qv * qv; s6q += q3v * q3v;
    s2k += kv * kv; s6k += k3v * k3v;
  }
  f32x4 s; s[0] = s2q; s[1] = s6q; s[2] = s2k; s[3] = s6k;
#pragma unroll
  for (int off = 32; off > 0; off >>= 1) {
    s[0] += __shfl_xor(s[0], off);
    s[1] += __shfl_xor(s[1], off);
    s[2] += __shfl_xor(s[2], off);
    s[3] += __shfl_xor(s[3], off);
  }
  const int wv = threadIdx.x >> 6;
  if ((threadIdx.x & 63) == 0) red[wv] = s;
  __syncthreads();
  f32x4 tot = red[0] + red[1] + red[2] + red[3];
  float fq = sqrtf(tot[0] / tot[1]);
  float fk = sqrtf(tot[2] / tot[3]);

  bf16x4 qo, ko;
#pragma unroll
  for (int j = 0; j < 4; j++) {
    qo[j] = (bf16)(q3[j] * fq);
    ko[j] = (bf16)(k3[j] * fk);
  }
  *(bf16x4*)(qp + row * 1024 + c0) = qo;
  *(bf16x4*)(kp + row * 1024 + c0) = ko;
}

// ---------------- kv = k^T v and ksum, partial over N/KSPLIT rows ----------------
__global__ __launch_bounds__(256) void kv_partial(const bf16* __restrict__ kp,
                                                  const bf16* __restrict__ vb,
                                                  float* __restrict__ kv_part,
                                                  float* __restrict__ ks_part) {
  __shared__ float kls[64 * 64];
  __shared__ float vls[64 * 64];
  const int sp = blockIdx.x;       // 0..KSPLIT-1
  const int bh = blockIdx.y;       // 0..127
  const int b = bh >> 4, h = bh & 15;
  const int tid = threadIdx.x;
  const int c0 = (tid & 15) * 4, d0 = (tid >> 4) * 4;

  f32x4 acc4[4] = {};
  float ks[4] = {0.f, 0.f, 0.f, 0.f};

  for (int chunk = 0; chunk < NSEQ / KSPLIT / 64; ++chunk) {
    const int n0 = sp * (NSEQ / KSPLIT) + chunk * 64;
    __syncthreads();
    for (int it = tid; it < 1024; it += 256) {
      int nn = it >> 4, cc = (it & 15) * 4;
      long g = ((long)(b * NSEQ + n0 + nn)) * NC + h * ND + cc;
      bf16x4 kb = *(const bf16x4*)(kp + g);
      bf16x4 vv = *(const bf16x4*)(vb + g);
      f32x4 kf, vf;
#pragma unroll
      for (int j = 0; j < 4; j++) { kf[j] = (float)kb[j]; vf[j] = (float)vv[j]; }
      *(f32x4*)&kls[nn * 64 + cc] = kf;
      *(f32x4*)&vls[nn * 64 + cc] = vf;
    }
    __syncthreads();
    for (int nn = 0; nn < 64; ++nn) {
      f32x4 kk = *(const f32x4*)&kls[nn * 64 + c0];
      f32x4 vv = *(const f32x4*)&vls[nn * 64 + d0];
#pragma unroll
      for (int i = 0; i < 4; i++) acc4[i] += kk[i] * vv;
      if (tid < 16) {
#pragma unroll
        for (int i = 0; i < 4; i++) ks[i] += kk[i];
      }
    }
  }
  const long base = ((long)(sp * NBH + bh)) * 4096;
#pragma unroll
  for (int i = 0; i < 4; i++)
    *(f32x4*)&kv_part[base + (c0 + i) * 64 + d0] = acc4[i];
  if (tid < 16) {
#pragma unroll
    for (int i = 0; i < 4; i++)
      ks_part[(long)(sp * NBH + bh) * 64 + c0 + i] = ks[i];
  }
}

__global__ __launch_bounds__(256) void reduce_parts(const float* __restrict__ src,
                                                    float* __restrict__ dst, int n) {
  int i = blockIdx.x * 256 + threadIdx.x;
  if (i < n) {
    float s = 0.f;
    for (int p = 0; p < KSPLIT; ++p) s += src[(long)p * n + i];
    dst[i] = s;
  }
}

// ---------------- z + o = z * q' @ kv ----------------
__global__ __launch_bounds__(256) void z_o(const bf16* __restrict__ qp,
                                           const float* __restrict__ kvm,
                                           const float* __restrict__ ksum,
                                           bf16* __restrict__ ob) {
  __shared__ float kvs[4096];
  __shared__ float kss[64];
  const int bh = blockIdx.x >> 4, chunk = blockIdx.x & 15;
  const int b = bh >> 4, h = bh & 15;
  const int tid = threadIdx.x;

  for (int i = tid; i < 1024; i += 256)
    *(f32x4*)&kvs[i * 4] = *(const f32x4*)&kvm[(long)bh * 4096 + i * 4];
  if (tid < 16)
    *(f32x4*)&kss[tid * 4] = *(const f32x4*)&ksum[(long)bh * 64 + tid * 4];
  __syncthreads();

  const int i = chunk * 256 + tid;   // row within sequence
  const bf16* qrow = qp + ((long)(b * NSEQ + i)) * NC + h * ND;

  float s = 0.f;
#pragma unroll
  for (int c8 = 0; c8 < 8; ++c8) {
    bf16x8 q8 = *(const bf16x8*)(qrow + c8 * 8);
#pragma unroll
    for (int j = 0; j < 8; j++) s += (float)q8[j] * kss[c8 * 8 + j];
  }
  const float z = 1.0f / (s + EPSF);

  f32x4 o4[16] = {};
  for (int c8 = 0; c8 < 8; ++c8) {
    bf16x8 q8 = *(const bf16x8*)(qrow + c8 * 8);
#pragma unroll
    for (int j = 0; j < 8; j++) {
      float qc = (float)q8[j];
      const f32x4* kr = (const f32x4*)&kvs[(c8 * 8 + j) * 64];
#pragma unroll
      for (int d4 = 0; d4 < 16; ++d4) o4[d4] += qc * kr[d4];
    }
  }
  bf16* orow = ob + ((long)(b * NSEQ + i)) * NC + h * ND;
#pragma unroll
  for (int d4 = 0; d4 < 16; ++d4) {
    bf16x4 o;
#pragma unroll
    for (int j = 0; j < 4; j++) o[j] = (bf16)(o4[d4][j] * z);
    *(bf16x4*)(orow + d4 * 4) = o;
  }
}

// ---------------- launch ----------------
extern "C" void kernel_launch(void* const* d_in, const int* in_sizes, int n_in,
                              void* d_out, int out_size, void* d_ws, size_t ws_size,
                              hipStream_t stream) {
  const float* x = (const float*)d_in[0];
  const float* scale = (const float*)d_in[1];
  const float* pos_enc = (const float*)d_in[2];
  const float* qkv_w = (const float*)d_in[3];
  const float* proj_w = (const float*)d_in[4];
  const float* proj_b = (const float*)d_in[5];
  float* out = (float*)d_out;

  char* ws = (char*)d_ws;
  size_t off = 0;
  auto alloc = [&](size_t bytes) {
    char* p = ws + off;
    off += (bytes + 255) & ~(size_t)255;
    return p;
  };
  bf16* xb = (bf16*)alloc((size_t)NM * NC * 2);          // 64 MB (reused as qp)
  bf16* wqkv = (bf16*)alloc((size_t)3 * NC * NC * 2);    // 6 MB
  bf16* wproj = (bf16*)alloc((size_t)NC * NC * 2);       // 2 MB
  float* inv_sc = (float*)alloc(NC * 4);
  bf16* peb = (bf16*)alloc((size_t)NSEQ * NC * 2);       // 8 MB
  bf16* vb = (bf16*)alloc((size_t)NM * NC * 2);          // 64 MB
  bf16* kp = (bf16*)alloc((size_t)NM * NC * 2);          // 64 MB
  float* ks_part = (float*)alloc((size_t)KSPLIT * NBH * ND * 4);
  float* ksum = (float*)alloc((size_t)NBH * ND * 4);
  float* kvm = (float*)alloc((size_t)NBH * ND * ND * 4); // 2 MB
  bf16* qkb = (bf16*)alloc((size_t)NM * 2048 * 2);       // 128 MB (dead after transform)
  (void)ws_size; (void)n_in; (void)in_sizes; (void)out_size;

  // aliases into the qkb region (qkb is dead after transform_qk):
  bf16* ob = (bf16*)qkb;                                       // 64 MB
  float* kv_part = (float*)((char*)qkb + (size_t)NM * NC * 2); // 16 MB
  bf16* qp = xb;                                               // xb dead after gemm_qkv

  // 1. converts
  cvt_bf16<<<dim3((NM * NC / 4 + 255) / 256), 256, 0, stream>>>(x, xb, NM * NC / 4);
  cvt_bf16<<<dim3((3 * NC * NC / 4 + 255) / 256), 256, 0, stream>>>(qkv_w, wqkv, 3 * NC * NC / 4);
  cvt_bf16<<<dim3((NC * NC / 4 + 255) / 256), 256, 0, stream>>>(proj_w, wproj, NC * NC / 4);
  cvt_bf16<<<dim3((NSEQ * NC / 4 + 255) / 256), 256, 0, stream>>>(pos_enc, peb, NSEQ * NC / 4);
  prep_scale<<<dim3(4), 256, 0, stream>>>(scale, inv_sc);

  // 2. qkv GEMM: (32768 x 1024) @ (3072 x 1024)^T  [256^2 tiles, 8-phase]
  gemm_bt8<0><<<dim3(12, 128), 512, 0, stream>>>(xb, wqkv, NC, qkb, vb, nullptr, nullptr);

  // 3. q/k transform
  transform_qk<<<dim3(NM), 256, 0, stream>>>(qkb, peb, inv_sc, qp, kp);

  // 4. kv / ksum
  kv_partial<<<dim3(KSPLIT, NBH), 256, 0, stream>>>(kp, vb, kv_part, ks_part);
  reduce_parts<<<dim3((NBH * ND + 255) / 256), 256, 0, stream>>>(ks_part, ksum, NBH * ND);
  reduce_parts<<<dim3((NBH * 4096 + 255) / 256), 256, 0, stream>>>(kv_part, kvm, NBH * 4096);

  // 5. z + o
  z_o<<<dim3(NBH * 16), 256, 0, stream>>>(qp, kvm, ksum, ob);

  // 6. proj GEMM + bias  [256^2 tiles, 8-phase]
  gemm_bt8<1><<<dim3(4, 128), 512, 0, stream>>>(ob, wproj, NC, nullptr, nullptr, out, proj_b);
}

// Round 4
// 750.192 us; speedup vs baseline: 1.2140x; 1.0885x over previous
//
#include <hip/hip_runtime.h>
#include <hip/hip_bf16.h>
#include <cstdint>
#include <cstddef>

// FocusedLinearAttention on MI355X (gfx950).
// R5: de-risked isolate. GEMM = R3's harness-verified 8-phase schedule
// (A(t+1)@P1/P2, B(t+2)@P3/P4, vmcnt(4)) — byte-identical to the run that
// measured 816 us total. New vs R3: (a) kv_partial -> kv_mfma (k^T v via
// transposed+XOR-swizzled LDS + MFMA, ksum via all-ones B fragment);
// (b) z_o 4-rows x d-quarter per thread (LDS traffic /4).

typedef __bf16 bf16;
typedef __bf16 bf16x4 __attribute__((ext_vector_type(4)));
typedef __bf16 bf16x8 __attribute__((ext_vector_type(8)));
typedef float f32x4 __attribute__((ext_vector_type(4)));
typedef float f32x2 __attribute__((ext_vector_type(2)));

#define NB 8
#define NSEQ 4096
#define NC 1024
#define NH 16
#define ND 64
#define NBH 128      // NB*NH
#define NM 32768     // NB*NSEQ
#define EPSF 1e-6f
#define KSPLIT 8

__device__ __forceinline__ void async16(const void* g, void* l) {
  __builtin_amdgcn_global_load_lds(
      (const __attribute__((address_space(1))) void*)g,
      (__attribute__((address_space(3))) void*)l, 16, 0, 0);
}

__device__ __forceinline__ unsigned pack_bf16(float a, float b) {
  union { bf16 h[2]; unsigned u; } t;
  t.h[0] = (bf16)a; t.h[1] = (bf16)b;
  return t.u;
}

#define BAR() asm volatile("s_barrier" ::: "memory")
#define WAIT_LGKM(N) asm volatile("s_waitcnt lgkmcnt(" #N ")" ::: "memory")
#define WAIT_VM(N) asm volatile("s_waitcnt vmcnt(" #N ")" ::: "memory")
#define SCHEDB() __builtin_amdgcn_sched_barrier(0)

// ---------------- fp32 -> bf16 convert ----------------
__global__ __launch_bounds__(256) void cvt_bf16(const float* __restrict__ src,
                                                bf16* __restrict__ dst, int n4) {
  int i = blockIdx.x * 256 + threadIdx.x;
  if (i < n4) {
    f32x4 v = ((const f32x4*)src)[i];
    bf16x4 o;
    o[0] = (bf16)v[0]; o[1] = (bf16)v[1]; o[2] = (bf16)v[2]; o[3] = (bf16)v[3];
    ((bf16x4*)dst)[i] = o;
  }
}

// ---------------- inv softplus(scale) ----------------
__global__ __launch_bounds__(256) void prep_scale(const float* __restrict__ scale,
                                                  float* __restrict__ inv_sc) {
  int c = blockIdx.x * 256 + threadIdx.x;
  if (c < NC) inv_sc[c] = 1.0f / log1pf(expf(scale[c]));
}

// ---------------- 256x256 bf16 MFMA GEMM, C = A @ B^T, 8-phase ----------------
// R3 schedule (harness-verified): A(t+1) staged @P1/P2 into buf q,
// B(t+2) staged @P3/P4 into buf p, vmcnt(4) once per K-tile.
template <int MODE>
__global__ __launch_bounds__(512, 2) void gemm_bt8(const bf16* __restrict__ A,
                                                   const bf16* __restrict__ Bm, int K,
                                                   bf16* __restrict__ outqk,
                                                   bf16* __restrict__ outv,
                                                   float* __restrict__ outf,
                                                   const float* __restrict__ bias) {
  __shared__ bf16 As[2 * 16384];
  __shared__ bf16 Bs[2 * 16384];

  const int tid = threadIdx.x;
  const int w = tid >> 6, lane = tid & 63;
  const int q4 = lane >> 4, l16 = lane & 15;
  const int l7 = l16 & 7;
  const int wm = (w >> 2) * 128, wn = (w & 3) * 64;   // wave -> 128x64 of C

  // T1: bijective XCD swizzle (nwg % 8 == 0 for all launches here)
  const int gx = gridDim.x;
  const int nwg = gx * gridDim.y;
  const int bid0 = blockIdx.y * gx + blockIdx.x;
  const int cpx = nwg >> 3;
  const int bid = (bid0 & 7) * cpx + (bid0 >> 3);
  const long row0 = (long)(bid / gx) * 256;
  const long col0 = (long)(bid % gx) * 256;

  // Staging geometry: slot s = w*128 + t2*64 + lane; LDS dest linear (slot*16B).
  // T2 swizzle applied on the GLOBAL SOURCE (rule 21): slot (r = s>>3, j = s&7)
  // holds global (row r, colgroup j ^ (r&7)). Involution; reads use same XOR.
  const int s0 = w * 128 + lane;                 // t2=0 slot (t2=1: +64)
  const int ra = s0 >> 3;                        // row within half-tile
  const int cg = ((s0 & 7) ^ (ra & 7)) << 3;     // source col element offset
  const int dl = s0 << 3;                        // LDS element offset within half

  const bf16* Abase = A + (row0 + ra) * (long)K + cg;
  const bf16* Bbase = Bm + (col0 + ra) * (long)K + cg;
  const long rstep = 8 * (long)K;                // +8 rows
  const long hstep = 128 * (long)K;              // +1 half-tile

  auto stA = [&](int buf, int h, int k0) {
    const bf16* g = Abase + h * hstep + k0;
    bf16* l = As + buf * 16384 + h * 8192 + dl;
    async16(g, l);
    async16(g + rstep, l + 512);
  };
  auto stB = [&](int buf, int h, int k0) {
    const bf16* g = Bbase + h * hstep + k0;
    bf16* l = Bs + buf * 16384 + h * 8192 + dl;
    async16(g, l);
    async16(g + rstep, l + 512);
  };

  const int nkt = K >> 6;

  // Prologue: K-tile0 (buf0) fully, K-tile1 B halves (buf1). Order matters
  // for the in-order vmcnt retirement: tile0's 8 loads are oldest.
  stA(0, 0, 0); stA(0, 1, 0);
  stB(0, 0, 0); stB(0, 1, 0);
  {
    const int k1p = (nkt > 1 ? 1 : 0) << 6;
    stB(1, 0, k1p); stB(1, 1, k1p);
  }
  WAIT_VM(4);   // K-tile0 resident; tile1 B stays in flight
  BAR();

  f32x4 acc[8][4] = {};
  bf16x8 af[4][2], bfr[4][2];

  for (int t = 0; t < nkt; ++t) {
    const int p = t & 1, q = p ^ 1;
    const int pb = p * 16384;
    const int k1 = (t + 1 < nkt ? t + 1 : nkt - 1) << 6;
    const int k2 = (t + 2 < nkt ? t + 2 : nkt - 1) << 6;

    // ---- P1: ld A(mhalf0) + B(ni0-1); stage A-h0(t+1)->buf q ----
#pragma unroll
    for (int mi = 0; mi < 4; mi++) {
      const int rb = (wm + mi * 16 + l16) * 64;
#pragma unroll
      for (int ks = 0; ks < 2; ks++)
        af[mi][ks] = *(const bf16x8*)&As[pb + rb + (((ks * 4 + q4) ^ l7) << 3)];
    }
#pragma unroll
    for (int ni = 0; ni < 2; ni++) {
      const int rb = (wn + ni * 16 + l16) * 64;
#pragma unroll
      for (int ks = 0; ks < 2; ks++)
        bfr[ni][ks] = *(const bf16x8*)&Bs[pb + rb + (((ks * 4 + q4) ^ l7) << 3)];
    }
    stA(q, 0, k1);
    WAIT_LGKM(8);
    BAR();
    WAIT_LGKM(0); SCHEDB();
    __builtin_amdgcn_s_setprio(1);
#pragma unroll
    for (int mi = 0; mi < 4; mi++)
#pragma unroll
      for (int ni = 0; ni < 2; ni++)
#pragma unroll
        for (int ks = 0; ks < 2; ks++)
          acc[mi][ni] = __builtin_amdgcn_mfma_f32_16x16x32_bf16(
              af[mi][ks], bfr[ni][ks], acc[mi][ni], 0, 0, 0);
    __builtin_amdgcn_s_setprio(0);
    BAR();

    // ---- P2: ld B(ni2-3); stage A-h1(t+1)->buf q ----
#pragma unroll
    for (int ni = 2; ni < 4; ni++) {
      const int rb = (wn + ni * 16 + l16) * 64;
#pragma unroll
      for (int ks = 0; ks < 2; ks++)
        bfr[ni][ks] = *(const bf16x8*)&Bs[pb + rb + (((ks * 4 + q4) ^ l7) << 3)];
    }
    stA(q, 1, k1);
    BAR();
    WAIT_LGKM(0); SCHEDB();
    __builtin_amdgcn_s_setprio(1);
#pragma unroll
    for (int mi = 0; mi < 4; mi++)
#pragma unroll
      for (int ni = 2; ni < 4; ni++)
#pragma unroll
        for (int ks = 0; ks < 2; ks++)
          acc[mi][ni] = __builtin_amdgcn_mfma_f32_16x16x32_bf16(
              af[mi][ks], bfr[ni][ks], acc[mi][ni], 0, 0, 0);
    __builtin_amdgcn_s_setprio(0);
    BAR();

    // ---- P3: ld A(mhalf1); stage B-h0(t+2)->buf p (B reads of p done @P2) ----
#pragma unroll
    for (int mi = 0; mi < 4; mi++) {
      const int rb = (wm + 64 + mi * 16 + l16) * 64;
#pragma unroll
      for (int ks = 0; ks < 2; ks++)
        af[mi][ks] = *(const bf16x8*)&As[pb + rb + (((ks * 4 + q4) ^ l7) << 3)];
    }
    stB(p, 0, k2);
    BAR();
    WAIT_LGKM(0); SCHEDB();
    __builtin_amdgcn_s_setprio(1);
#pragma unroll
    for (int mi = 0; mi < 4; mi++)
#pragma unroll
      for (int ni = 0; ni < 2; ni++)
#pragma unroll
        for (int ks = 0; ks < 2; ks++)
          acc[4 + mi][ni] = __builtin_amdgcn_mfma_f32_16x16x32_bf16(
              af[mi][ks], bfr[ni][ks], acc[4 + mi][ni], 0, 0, 0);
    __builtin_amdgcn_s_setprio(0);
    BAR();

    // ---- P4: stage B-h1(t+2)->buf p; MFMA from regs; counted vmcnt ----
    stB(p, 1, k2);
    BAR();
    __builtin_amdgcn_s_setprio(1);
#pragma unroll
    for (int mi = 0; mi < 4; mi++)
#pragma unroll
      for (int ni = 2; ni < 4; ni++)
#pragma unroll
        for (int ks = 0; ks < 2; ks++)
          acc[4 + mi][ni] = __builtin_amdgcn_mfma_f32_16x16x32_bf16(
              af[mi][ks], bfr[ni][ks], acc[4 + mi][ni], 0, 0, 0);
    __builtin_amdgcn_s_setprio(0);
    WAIT_VM(4);   // all of K-tile t+1 resident; only B(t+2) (4 loads) in flight
    BAR();
  }
  WAIT_VM(0);     // drain trailing stages before epilogue/exit

  // ---- packed-pair epilogue (same mapping as verified R2) ----
  const int ev = (l16 & 1) == 0;
#pragma unroll
  for (int mi = 0; mi < 8; mi++) {
    long gr0 = row0 + wm + mi * 16 + q4 * 4;
#pragma unroll
    for (int ni = 0; ni < 4; ni++) {
      long gc = col0 + wn + ni * 16 + l16;
      long cb = gc & ~1L;
      long r2 = gr0 + (ev ? 0 : 2);
      if (MODE == 0) {
        unsigned m01 = pack_bf16(acc[mi][ni][0], acc[mi][ni][1]);
        unsigned m23 = pack_bf16(acc[mi][ni][2], acc[mi][ni][3]);
        unsigned p01 = __shfl_xor(m01, 1);
        unsigned p23 = __shfl_xor(m23, 1);
        unsigned xs = ev ? m01 : p23;
        unsigned ys = ev ? p01 : m23;
        unsigned da = (xs & 0xFFFFu) | (ys << 16);
        unsigned db = (xs >> 16) | (ys & 0xFFFF0000u);
        if (col0 < 2048) {
          *(unsigned*)(outqk + r2 * 2048 + cb) = da;
          *(unsigned*)(outqk + (r2 + 1) * 2048 + cb) = db;
        } else {
          *(unsigned*)(outv + r2 * 1024 + (cb - 2048)) = da;
          *(unsigned*)(outv + (r2 + 1) * 1024 + (cb - 2048)) = db;
        }
      } else {
        float bsum = bias[gc];
        float v0 = acc[mi][ni][0] + bsum, v1 = acc[mi][ni][1] + bsum;
        float v2 = acc[mi][ni][2] + bsum, v3 = acc[mi][ni][3] + bsum;
        float p0 = __shfl_xor(v0, 1), p1 = __shfl_xor(v1, 1);
        float p2 = __shfl_xor(v2, 1), p3 = __shfl_xor(v3, 1);
        f32x2 sa, sb;
        sa[0] = ev ? v0 : p2; sa[1] = ev ? p0 : v2;
        sb[0] = ev ? v1 : p3; sb[1] = ev ? p1 : v3;
        *(f32x2*)(outf + r2 * 1024 + cb) = sa;
        *(f32x2*)(outf + (r2 + 1) * 1024 + cb) = sb;
      }
    }
  }
}

// ---------------- q/k nonlinear transform (per row over C=1024) ----------------
__global__ __launch_bounds__(256) void transform_qk(const bf16* __restrict__ qkb,
                                                    const bf16* __restrict__ peb,
                                                    const float* __restrict__ inv_sc,
                                                    bf16* __restrict__ qp,
                                                    bf16* __restrict__ kp) {
  __shared__ f32x4 red[4];
  const long row = blockIdx.x;          // 0..NM-1
  const int n = (int)(row & (NSEQ - 1));
  const int c0 = threadIdx.x * 4;

  bf16x4 qb = *(const bf16x4*)(qkb + row * 2048 + c0);
  bf16x4 kb = *(const bf16x4*)(qkb + row * 2048 + 1024 + c0);
  bf16x4 pe = *(const bf16x4*)(peb + (long)n * 1024 + c0);
  f32x4 isc = *(const f32x4*)(inv_sc + c0);

  f32x4 q3, k3;
  float s2q = 0, s6q = 0, s2k = 0, s6k = 0;
#pragma unroll
  for (int j = 0; j < 4; j++) {
    float qv = (fmaxf((float)qb[j], 0.f) + EPSF) * isc[j];
    float kv = (fmaxf((float)kb[j] + (float)pe[j], 0.f) + EPSF) * isc[j];
    float q3v = qv * qv * qv, k3v = kv * kv * kv;
    q3[j] = q3v; k3[j] = k3v;
    s2q += qv * qv; s6q += q3v * q3v;
    s2k += kv * kv; s6k += k3v * k3v;
  }
  f32x4 s; s[0] = s2q; s[1] = s6q; s[2] = s2k; s[3] = s6k;
#pragma unroll
  for (int off = 32; off > 0; off >>= 1) {
    s[0] += __shfl_xor(s[0], off);
    s[1] += __shfl_xor(s[1], off);
    s[2] += __shfl_xor(s[2], off);
    s[3] += __shfl_xor(s[3], off);
  }
  const int wv = threadIdx.x >> 6;
  if ((threadIdx.x & 63) == 0) red[wv] = s;
  __syncthreads();
  f32x4 tot = red[0] + red[1] + red[2] + red[3];
  float fq = sqrtf(tot[0] / tot[1]);
  float fk = sqrtf(tot[2] / tot[3]);

  bf16x4 qo, ko;
#pragma unroll
  for (int j = 0; j < 4; j++) {
    qo[j] = (bf16)(q3[j] * fq);
    ko[j] = (bf16)(k3[j] * fk);
  }
  *(bf16x4*)(qp + row * 1024 + c0) = qo;
  *(bf16x4*)(kp + row * 1024 + c0) = ko;
}

// ---------------- kv = k^T v and ksum via MFMA, partial over N/KSPLIT ----------
// Per block: one (sp, bh). LDS holds transposed+XOR-swizzled 64n-chunks:
// kT[c][n], vT[d][n] (element (r, n) at r*64 + ((n>>3 ^ (r&7))<<3) + (n&7)).
// Wave w computes c-rows [w*16, w*16+16) x d[0,64): A-frag from kT rows,
// B-frag from vT rows (mirror of gemm_bt8's fragment read paths).
// ksum[c] via MFMA with an all-ones B fragment (C[c][*] = sum_n k[n][c]).
__global__ __launch_bounds__(256) void kv_mfma(const bf16* __restrict__ kp,
                                               const bf16* __restrict__ vb,
                                               float* __restrict__ kv_part,
                                               float* __restrict__ ks_part) {
  __shared__ bf16 kT[64 * 64];
  __shared__ bf16 vT[64 * 64];
  const int sp = blockIdx.x;       // 0..KSPLIT-1
  const int bh = blockIdx.y;       // 0..127
  const int b = bh >> 4, h = bh & 15;
  const int tid = threadIdx.x;
  const int w = tid >> 6, lane = tid & 63;
  const int q4 = lane >> 4, l16 = lane & 15;
  const int nn = tid >> 2, cg = (tid & 3) * 16;   // staging: row n, 16 cols

  f32x4 acc[4] = {};
  f32x4 aks = {};
  bf16x8 ones;
#pragma unroll
  for (int j = 0; j < 8; j++) ones[j] = (bf16)1.0f;

  for (int chunk = 0; chunk < NSEQ / KSPLIT / 64; ++chunk) {
    const int n0 = sp * (NSEQ / KSPLIT) + chunk * 64;
    __syncthreads();   // previous chunk's reads done before overwrite
    {
      const long g = ((long)(b * NSEQ + n0 + nn)) * NC + h * ND + cg;
      bf16x8 k0 = *(const bf16x8*)(kp + g);
      bf16x8 k1 = *(const bf16x8*)(kp + g + 8);
      bf16x8 v0 = *(const bf16x8*)(vb + g);
      bf16x8 v1 = *(const bf16x8*)(vb + g + 8);
#pragma unroll
      for (int j = 0; j < 8; j++) {
        const int c = cg + j;
        const int idx = c * 64 + (((nn >> 3) ^ (c & 7)) << 3) + (nn & 7);
        kT[idx] = k0[j]; vT[idx] = v0[j];
        const int c2 = cg + 8 + j;
        const int idx2 = c2 * 64 + (((nn >> 3) ^ (c2 & 7)) << 3) + (nn & 7);
        kT[idx2] = k1[j]; vT[idx2] = v1[j];
      }
    }
    __syncthreads();
#pragma unroll
    for (int kk = 0; kk < 2; kk++) {
      const int cA = w * 16 + l16;
      bf16x8 af = *(const bf16x8*)&kT[cA * 64 + (((kk * 4 + q4) ^ (cA & 7)) << 3)];
#pragma unroll
      for (int dt = 0; dt < 4; dt++) {
        const int dR = dt * 16 + l16;
        bf16x8 bf_ = *(const bf16x8*)&vT[dR * 64 + (((kk * 4 + q4) ^ (dR & 7)) << 3)];
        acc[dt] = __builtin_amdgcn_mfma_f32_16x16x32_bf16(af, bf_, acc[dt], 0, 0, 0);
      }
      aks = __builtin_amdgcn_mfma_f32_16x16x32_bf16(af, ones, aks, 0, 0, 0);
    }
  }
  // C/D layout: row(c) = q4*4 + ri, col(d) = l16 (verified mapping)
  const long base = ((long)(sp * NBH + bh)) * 4096;
  const int c0 = w * 16 + q4 * 4;
#pragma unroll
  for (int ri = 0; ri < 4; ri++) {
#pragma unroll
    for (int dt = 0; dt < 4; dt++)
      kv_part[base + (long)(c0 + ri) * 64 + dt * 16 + l16] = acc[dt][ri];
  }
  if (l16 == 0) {
#pragma unroll
    for (int ri = 0; ri < 4; ri++)
      ks_part[(long)(sp * NBH + bh) * 64 + c0 + ri] = aks[ri];
  }
}

__global__ __launch_bounds__(256) void reduce_parts(const float* __restrict__ src,
                                                    float* __restrict__ dst, int n) {
  int i = blockIdx.x * 256 + threadIdx.x;
  if (i < n) {
    float s = 0.f;
    for (int p = 0; p < KSPLIT; ++p) s += src[(long)p * n + i];
    dst[i] = s;
  }
}

// ---------------- z + o = z * q' @ kv ----------------
// v3: thread = 4 rows x one d-quarter. Each kv row-slice read from LDS once
// per 4 rows (LDS traffic /4); s computed redundantly per quarter.
__global__ __launch_bounds__(256) void z_o(const bf16* __restrict__ qp,
                                           const float* __restrict__ kvm,
                                           const float* __restrict__ ksum,
                                           bf16* __restrict__ ob) {
  __shared__ float kvs[4096];
  __shared__ float kss[64];
  const int bh = blockIdx.x >> 4, chunk = blockIdx.x & 15;
  const int b = bh >> 4, h = bh & 15;
  const int tid = threadIdx.x;
  const int rg = tid >> 2;          // row group 0..63 (4 rows each)
  const int qd = (tid & 3) * 16;    // d-quarter offset

  for (int i = tid; i < 1024; i += 256)
    *(f32x4*)&kvs[i * 4] = *(const f32x4*)&kvm[(long)bh * 4096 + i * 4];
  if (tid < 16)
    *(f32x4*)&kss[tid * 4] = *(const f32x4*)&ksum[(long)bh * 64 + tid * 4];
  __syncthreads();

  const long i0 = (long)b * NSEQ + chunk * 256 + rg * 4;   // first of 4 rows
  const bf16* q0 = qp + i0 * NC + h * ND;

  f32x4 o4[4][4] = {};
  float s[4] = {0.f, 0.f, 0.f, 0.f};
  for (int c8 = 0; c8 < 8; ++c8) {
    bf16x8 q8[4];
#pragma unroll
    for (int r = 0; r < 4; r++) q8[r] = *(const bf16x8*)(q0 + r * NC + c8 * 8);
#pragma unroll
    for (int j = 0; j < 8; j++) {
      const int c = c8 * 8 + j;
      const f32x4* kr = (const f32x4*)&kvs[c * 64 + qd];
      const f32x4 k0 = kr[0], k1 = kr[1], k2 = kr[2], k3 = kr[3];
      const float ksc = kss[c];
#pragma unroll
      for (int r = 0; r < 4; r++) {
        const float qc = (float)q8[r][j];
        o4[r][0] += qc * k0; o4[r][1] += qc * k1;
        o4[r][2] += qc * k2; o4[r][3] += qc * k3;
        s[r] += qc * ksc;
      }
    }
  }
#pragma unroll
  for (int r = 0; r < 4; r++) {
    const float z = 1.0f / (s[r] + EPSF);
    bf16* orow = ob + (i0 + r) * NC + h * ND + qd;
#pragma unroll
    for (int d4 = 0; d4 < 4; d4++) {
      bf16x4 o;
#pragma unroll
      for (int j = 0; j < 4; j++) o[j] = (bf16)(o4[r][d4][j] * z);
      *(bf16x4*)(orow + d4 * 4) = o;
    }
  }
}

// ---------------- launch ----------------
extern "C" void kernel_launch(void* const* d_in, const int* in_sizes, int n_in,
                              void* d_out, int out_size, void* d_ws, size_t ws_size,
                              hipStream_t stream) {
  const float* x = (const float*)d_in[0];
  const float* scale = (const float*)d_in[1];
  const float* pos_enc = (const float*)d_in[2];
  const float* qkv_w = (const float*)d_in[3];
  const float* proj_w = (const float*)d_in[4];
  const float* proj_b = (const float*)d_in[5];
  float* out = (float*)d_out;

  char* ws = (char*)d_ws;
  size_t off = 0;
  auto alloc = [&](size_t bytes) {
    char* p = ws + off;
    off += (bytes + 255) & ~(size_t)255;
    return p;
  };
  bf16* xb = (bf16*)alloc((size_t)NM * NC * 2);          // 64 MB (reused as qp)
  bf16* wqkv = (bf16*)alloc((size_t)3 * NC * NC * 2);    // 6 MB
  bf16* wproj = (bf16*)alloc((size_t)NC * NC * 2);       // 2 MB
  float* inv_sc = (float*)alloc(NC * 4);
  bf16* peb = (bf16*)alloc((size_t)NSEQ * NC * 2);       // 8 MB
  bf16* vb = (bf16*)alloc((size_t)NM * NC * 2);          // 64 MB
  bf16* kp = (bf16*)alloc((size_t)NM * NC * 2);          // 64 MB
  float* ks_part = (float*)alloc((size_t)KSPLIT * NBH * ND * 4);
  float* ksum = (float*)alloc((size_t)NBH * ND * 4);
  float* kvm = (float*)alloc((size_t)NBH * ND * ND * 4); // 2 MB
  bf16* qkb = (bf16*)alloc((size_t)NM * 2048 * 2);       // 128 MB (dead after transform)
  (void)ws_size; (void)n_in; (void)in_sizes; (void)out_size;

  // aliases into the qkb region (qkb is dead after transform_qk):
  bf16* ob = (bf16*)qkb;                                       // 64 MB
  float* kv_part = (float*)((char*)qkb + (size_t)NM * NC * 2); // 16 MB
  bf16* qp = xb;                                               // xb dead after gemm_qkv

  // 1. converts
  cvt_bf16<<<dim3((NM * NC / 4 + 255) / 256), 256, 0, stream>>>(x, xb, NM * NC / 4);
  cvt_bf16<<<dim3((3 * NC * NC / 4 + 255) / 256), 256, 0, stream>>>(qkv_w, wqkv, 3 * NC * NC / 4);
  cvt_bf16<<<dim3((NC * NC / 4 + 255) / 256), 256, 0, stream>>>(proj_w, wproj, NC * NC / 4);
  cvt_bf16<<<dim3((NSEQ * NC / 4 + 255) / 256), 256, 0, stream>>>(pos_enc, peb, NSEQ * NC / 4);
  prep_scale<<<dim3(4), 256, 0, stream>>>(scale, inv_sc);

  // 2. qkv GEMM: (32768 x 1024) @ (3072 x 1024)^T  [256^2 tiles, 8-phase]
  gemm_bt8<0><<<dim3(12, 128), 512, 0, stream>>>(xb, wqkv, NC, qkb, vb, nullptr, nullptr);

  // 3. q/k transform
  transform_qk<<<dim3(NM), 256, 0, stream>>>(qkb, peb, inv_sc, qp, kp);

  // 4. kv / ksum (MFMA)
  kv_mfma<<<dim3(KSPLIT, NBH), 256, 0, stream>>>(kp, vb, kv_part, ks_part);
  reduce_parts<<<dim3((NBH * ND + 255) / 256), 256, 0, stream>>>(ks_part, ksum, NBH * ND);
  reduce_parts<<<dim3((NBH * 4096 + 255) / 256), 256, 0, stream>>>(kv_part, kvm, NBH * 4096);

  // 5. z + o
  z_o<<<dim3(NBH * 16), 256, 0, stream>>>(qp, kvm, ksum, ob);

  // 6. proj GEMM + bias  [256^2 tiles, 8-phase]
  gemm_bt8<1><<<dim3(4, 128), 512, 0, stream>>>(ob, wproj, NC, nullptr, nullptr, out, proj_b);
}

// Round 5
// 727.659 us; speedup vs baseline: 1.2516x; 1.0310x over previous
//
#include <hip/hip_runtime.h>
#include <hip/hip_bf16.h>
#include <cstdint>
#include <cstddef>

// FocusedLinearAttention on MI355X (gfx950).
// R6: GEMM phases de-serialized — removed mid-phase barrier + monolithic
// lgkmcnt(0); compiler now emits fine-grained per-operand lgkmcnt so the
// LDS-read pipe (2300 cyc/K-tile/CU) overlaps the MFMA pipe (2480 cyc)
// instead of adding. One barrier per phase; all double-buffer hazards are
// enforced by end-of-phase barriers (stage into a region happens >=1
// end-barrier after the MFMAs that consumed it; MFMA issue proves operand
// reads complete). vmcnt(4) per K-tile unchanged from verified R3/R5.
// kv_mfma + z_o byte-identical to passing R5.

typedef __bf16 bf16;
typedef __bf16 bf16x4 __attribute__((ext_vector_type(4)));
typedef __bf16 bf16x8 __attribute__((ext_vector_type(8)));
typedef float f32x4 __attribute__((ext_vector_type(4)));
typedef float f32x2 __attribute__((ext_vector_type(2)));

#define NB 8
#define NSEQ 4096
#define NC 1024
#define NH 16
#define ND 64
#define NBH 128      // NB*NH
#define NM 32768     // NB*NSEQ
#define EPSF 1e-6f
#define KSPLIT 8

__device__ __forceinline__ void async16(const void* g, void* l) {
  __builtin_amdgcn_global_load_lds(
      (const __attribute__((address_space(1))) void*)g,
      (__attribute__((address_space(3))) void*)l, 16, 0, 0);
}

__device__ __forceinline__ unsigned pack_bf16(float a, float b) {
  union { bf16 h[2]; unsigned u; } t;
  t.h[0] = (bf16)a; t.h[1] = (bf16)b;
  return t.u;
}

#define BAR() asm volatile("s_barrier" ::: "memory")
#define WAIT_VM(N) asm volatile("s_waitcnt vmcnt(" #N ")" ::: "memory")

// ---------------- fp32 -> bf16 convert ----------------
__global__ __launch_bounds__(256) void cvt_bf16(const float* __restrict__ src,
                                                bf16* __restrict__ dst, int n4) {
  int i = blockIdx.x * 256 + threadIdx.x;
  if (i < n4) {
    f32x4 v = ((const f32x4*)src)[i];
    bf16x4 o;
    o[0] = (bf16)v[0]; o[1] = (bf16)v[1]; o[2] = (bf16)v[2]; o[3] = (bf16)v[3];
    ((bf16x4*)dst)[i] = o;
  }
}

// ---------------- inv softplus(scale) ----------------
__global__ __launch_bounds__(256) void prep_scale(const float* __restrict__ scale,
                                                  float* __restrict__ inv_sc) {
  int c = blockIdx.x * 256 + threadIdx.x;
  if (c < NC) inv_sc[c] = 1.0f / log1pf(expf(scale[c]));
}

// ---------------- 256x256 bf16 MFMA GEMM, C = A @ B^T, 4x1-barrier phases ---
// Stage placement (verified R3): A(t+1)@P1/P2 -> buf q, B(t+2)@P3/P4 -> buf p,
// vmcnt(4) once per K-tile at end-P4.
template <int MODE>
__global__ __launch_bounds__(512, 2) void gemm_bt8(const bf16* __restrict__ A,
                                                   const bf16* __restrict__ Bm, int K,
                                                   bf16* __restrict__ outqk,
                                                   bf16* __restrict__ outv,
                                                   float* __restrict__ outf,
                                                   const float* __restrict__ bias) {
  __shared__ bf16 As[2 * 16384];
  __shared__ bf16 Bs[2 * 16384];

  const int tid = threadIdx.x;
  const int w = tid >> 6, lane = tid & 63;
  const int q4 = lane >> 4, l16 = lane & 15;
  const int l7 = l16 & 7;
  const int wm = (w >> 2) * 128, wn = (w & 3) * 64;   // wave -> 128x64 of C

  // T1: bijective XCD swizzle (nwg % 8 == 0 for all launches here)
  const int gx = gridDim.x;
  const int nwg = gx * gridDim.y;
  const int bid0 = blockIdx.y * gx + blockIdx.x;
  const int cpx = nwg >> 3;
  const int bid = (bid0 & 7) * cpx + (bid0 >> 3);
  const long row0 = (long)(bid / gx) * 256;
  const long col0 = (long)(bid % gx) * 256;

  // Staging geometry: slot s = w*128 + t2*64 + lane; LDS dest linear (slot*16B).
  // T2 swizzle applied on the GLOBAL SOURCE (rule 21): slot (r = s>>3, j = s&7)
  // holds global (row r, colgroup j ^ (r&7)). Involution; reads use same XOR.
  const int s0 = w * 128 + lane;                 // t2=0 slot (t2=1: +64)
  const int ra = s0 >> 3;                        // row within half-tile
  const int cg = ((s0 & 7) ^ (ra & 7)) << 3;     // source col element offset
  const int dl = s0 << 3;                        // LDS element offset within half

  const bf16* Abase = A + (row0 + ra) * (long)K + cg;
  const bf16* Bbase = Bm + (col0 + ra) * (long)K + cg;
  const long rstep = 8 * (long)K;                // +8 rows
  const long hstep = 128 * (long)K;              // +1 half-tile

  auto stA = [&](int buf, int h, int k0) {
    const bf16* g = Abase + h * hstep + k0;
    bf16* l = As + buf * 16384 + h * 8192 + dl;
    async16(g, l);
    async16(g + rstep, l + 512);
  };
  auto stB = [&](int buf, int h, int k0) {
    const bf16* g = Bbase + h * hstep + k0;
    bf16* l = Bs + buf * 16384 + h * 8192 + dl;
    async16(g, l);
    async16(g + rstep, l + 512);
  };

  const int nkt = K >> 6;

  // Prologue: K-tile0 (buf0) fully, K-tile1 B halves (buf1). Order matters
  // for the in-order vmcnt retirement: tile0's 8 loads are oldest.
  stA(0, 0, 0); stA(0, 1, 0);
  stB(0, 0, 0); stB(0, 1, 0);
  {
    const int k1p = (nkt > 1 ? 1 : 0) << 6;
    stB(1, 0, k1p); stB(1, 1, k1p);
  }
  WAIT_VM(4);   // K-tile0 resident; tile1 B stays in flight
  BAR();

  f32x4 acc[8][4] = {};
  bf16x8 af[4][2], bfr[4][2];

  for (int t = 0; t < nkt; ++t) {
    const int p = t & 1, q = p ^ 1;
    const int pb = p * 16384;
    const int k1 = (t + 1 < nkt ? t + 1 : nkt - 1) << 6;
    const int k2 = (t + 2 < nkt ? t + 2 : nkt - 1) << 6;

    // ---- P1: ld A(mhalf0)+B(ni0-1); stage A-h0(t+1)->buf q; MFMA Q(h0,n01) --
#pragma unroll
    for (int mi = 0; mi < 4; mi++) {
      const int rb = (wm + mi * 16 + l16) * 64;
#pragma unroll
      for (int ks = 0; ks < 2; ks++)
        af[mi][ks] = *(const bf16x8*)&As[pb + rb + (((ks * 4 + q4) ^ l7) << 3)];
    }
#pragma unroll
    for (int ni = 0; ni < 2; ni++) {
      const int rb = (wn + ni * 16 + l16) * 64;
#pragma unroll
      for (int ks = 0; ks < 2; ks++)
        bfr[ni][ks] = *(const bf16x8*)&Bs[pb + rb + (((ks * 4 + q4) ^ l7) << 3)];
    }
    stA(q, 0, k1);
    __builtin_amdgcn_s_setprio(1);
#pragma unroll
    for (int mi = 0; mi < 4; mi++)
#pragma unroll
      for (int ni = 0; ni < 2; ni++)
#pragma unroll
        for (int ks = 0; ks < 2; ks++)
          acc[mi][ni] = __builtin_amdgcn_mfma_f32_16x16x32_bf16(
              af[mi][ks], bfr[ni][ks], acc[mi][ni], 0, 0, 0);
    __builtin_amdgcn_s_setprio(0);
    BAR();

    // ---- P2: ld B(ni2-3); stage A-h1(t+1)->buf q; MFMA Q(h0,n23) ----
#pragma unroll
    for (int ni = 2; ni < 4; ni++) {
      const int rb = (wn + ni * 16 + l16) * 64;
#pragma unroll
      for (int ks = 0; ks < 2; ks++)
        bfr[ni][ks] = *(const bf16x8*)&Bs[pb + rb + (((ks * 4 + q4) ^ l7) << 3)];
    }
    stA(q, 1, k1);
    __builtin_amdgcn_s_setprio(1);
#pragma unroll
    for (int mi = 0; mi < 4; mi++)
#pragma unroll
      for (int ni = 2; ni < 4; ni++)
#pragma unroll
        for (int ks = 0; ks < 2; ks++)
          acc[mi][ni] = __builtin_amdgcn_mfma_f32_16x16x32_bf16(
              af[mi][ks], bfr[ni][ks], acc[mi][ni], 0, 0, 0);
    __builtin_amdgcn_s_setprio(0);
    BAR();

    // ---- P3: ld A(mhalf1); stage B-h0(t+2)->buf p (B reads of p consumed
    //      by P2's MFMAs before the P2 end-barrier); MFMA Q(h1,n01) ----
#pragma unroll
    for (int mi = 0; mi < 4; mi++) {
      const int rb = (wm + 64 + mi * 16 + l16) * 64;
#pragma unroll
      for (int ks = 0; ks < 2; ks++)
        af[mi][ks] = *(const bf16x8*)&As[pb + rb + (((ks * 4 + q4) ^ l7) << 3)];
    }
    stB(p, 0, k2);
    __builtin_amdgcn_s_setprio(1);
#pragma unroll
    for (int mi = 0; mi < 4; mi++)
#pragma unroll
      for (int ni = 0; ni < 2; ni++)
#pragma unroll
        for (int ks = 0; ks < 2; ks++)
          acc[4 + mi][ni] = __builtin_amdgcn_mfma_f32_16x16x32_bf16(
              af[mi][ks], bfr[ni][ks], acc[4 + mi][ni], 0, 0, 0);
    __builtin_amdgcn_s_setprio(0);
    BAR();

    // ---- P4: stage B-h1(t+2)->buf p; MFMA Q(h1,n23) from regs; vmcnt(4) ----
    stB(p, 1, k2);
    __builtin_amdgcn_s_setprio(1);
#pragma unroll
    for (int mi = 0; mi < 4; mi++)
#pragma unroll
      for (int ni = 2; ni < 4; ni++)
#pragma unroll
        for (int ks = 0; ks < 2; ks++)
          acc[4 + mi][ni] = __builtin_amdgcn_mfma_f32_16x16x32_bf16(
              af[mi][ks], bfr[ni][ks], acc[4 + mi][ni], 0, 0, 0);
    __builtin_amdgcn_s_setprio(0);
    WAIT_VM(4);   // all of K-tile t+1 resident; only B(t+2) (4 loads) in flight
    BAR();
  }
  WAIT_VM(0);     // drain trailing stages before epilogue/exit

  // ---- packed-pair epilogue (same mapping as verified R2) ----
  const int ev = (l16 & 1) == 0;
#pragma unroll
  for (int mi = 0; mi < 8; mi++) {
    long gr0 = row0 + wm + mi * 16 + q4 * 4;
#pragma unroll
    for (int ni = 0; ni < 4; ni++) {
      long gc = col0 + wn + ni * 16 + l16;
      long cb = gc & ~1L;
      long r2 = gr0 + (ev ? 0 : 2);
      if (MODE == 0) {
        unsigned m01 = pack_bf16(acc[mi][ni][0], acc[mi][ni][1]);
        unsigned m23 = pack_bf16(acc[mi][ni][2], acc[mi][ni][3]);
        unsigned p01 = __shfl_xor(m01, 1);
        unsigned p23 = __shfl_xor(m23, 1);
        unsigned xs = ev ? m01 : p23;
        unsigned ys = ev ? p01 : m23;
        unsigned da = (xs & 0xFFFFu) | (ys << 16);
        unsigned db = (xs >> 16) | (ys & 0xFFFF0000u);
        if (col0 < 2048) {
          *(unsigned*)(outqk + r2 * 2048 + cb) = da;
          *(unsigned*)(outqk + (r2 + 1) * 2048 + cb) = db;
        } else {
          *(unsigned*)(outv + r2 * 1024 + (cb - 2048)) = da;
          *(unsigned*)(outv + (r2 + 1) * 1024 + (cb - 2048)) = db;
        }
      } else {
        float bsum = bias[gc];
        float v0 = acc[mi][ni][0] + bsum, v1 = acc[mi][ni][1] + bsum;
        float v2 = acc[mi][ni][2] + bsum, v3 = acc[mi][ni][3] + bsum;
        float p0 = __shfl_xor(v0, 1), p1 = __shfl_xor(v1, 1);
        float p2 = __shfl_xor(v2, 1), p3 = __shfl_xor(v3, 1);
        f32x2 sa, sb;
        sa[0] = ev ? v0 : p2; sa[1] = ev ? p0 : v2;
        sb[0] = ev ? v1 : p3; sb[1] = ev ? p1 : v3;
        *(f32x2*)(outf + r2 * 1024 + cb) = sa;
        *(f32x2*)(outf + (r2 + 1) * 1024 + cb) = sb;
      }
    }
  }
}

// ---------------- q/k nonlinear transform (per row over C=1024) ----------------
__global__ __launch_bounds__(256) void transform_qk(const bf16* __restrict__ qkb,
                                                    const bf16* __restrict__ peb,
                                                    const float* __restrict__ inv_sc,
                                                    bf16* __restrict__ qp,
                                                    bf16* __restrict__ kp) {
  __shared__ f32x4 red[4];
  const long row = blockIdx.x;          // 0..NM-1
  const int n = (int)(row & (NSEQ - 1));
  const int c0 = threadIdx.x * 4;

  bf16x4 qb = *(const bf16x4*)(qkb + row * 2048 + c0);
  bf16x4 kb = *(const bf16x4*)(qkb + row * 2048 + 1024 + c0);
  bf16x4 pe = *(const bf16x4*)(peb + (long)n * 1024 + c0);
  f32x4 isc = *(const f32x4*)(inv_sc + c0);

  f32x4 q3, k3;
  float s2q = 0, s6q = 0, s2k = 0, s6k = 0;
#pragma unroll
  for (int j = 0; j < 4; j++) {
    float qv = (fmaxf((float)qb[j], 0.f) + EPSF) * isc[j];
    float kv = (fmaxf((float)kb[j] + (float)pe[j], 0.f) + EPSF) * isc[j];
    float q3v = qv * qv * qv, k3v = kv * kv * kv;
    q3[j] = q3v; k3[j] = k3v;
    s2q += qv * qv; s6q += q3v * q3v;
    s2k += kv * kv; s6k += k3v * k3v;
  }
  f32x4 s; s[0] = s2q; s[1] = s6q; s[2] = s2k; s[3] = s6k;
#pragma unroll
  for (int off = 32; off > 0; off >>= 1) {
    s[0] += __shfl_xor(s[0], off);
    s[1] += __shfl_xor(s[1], off);
    s[2] += __shfl_xor(s[2], off);
    s[3] += __shfl_xor(s[3], off);
  }
  const int wv = threadIdx.x >> 6;
  if ((threadIdx.x & 63) == 0) red[wv] = s;
  __syncthreads();
  f32x4 tot = red[0] + red[1] + red[2] + red[3];
  float fq = sqrtf(tot[0] / tot[1]);
  float fk = sqrtf(tot[2] / tot[3]);

  bf16x4 qo, ko;
#pragma unroll
  for (int j = 0; j < 4; j++) {
    qo[j] = (bf16)(q3[j] * fq);
    ko[j] = (bf16)(k3[j] * fk);
  }
  *(bf16x4*)(qp + row * 1024 + c0) = qo;
  *(bf16x4*)(kp + row * 1024 + c0) = ko;
}

// ---------------- kv = k^T v and ksum via MFMA, partial over N/KSPLIT ----------
__global__ __launch_bounds__(256) void kv_mfma(const bf16* __restrict__ kp,
                                               const bf16* __restrict__ vb,
                                               float* __restrict__ kv_part,
                                               float* __restrict__ ks_part) {
  __shared__ bf16 kT[64 * 64];
  __shared__ bf16 vT[64 * 64];
  const int sp = blockIdx.x;       // 0..KSPLIT-1
  const int bh = blockIdx.y;       // 0..127
  const int b = bh >> 4, h = bh & 15;
  const int tid = threadIdx.x;
  const int w = tid >> 6, lane = tid & 63;
  const int q4 = lane >> 4, l16 = lane & 15;
  const int nn = tid >> 2, cg = (tid & 3) * 16;   // staging: row n, 16 cols

  f32x4 acc[4] = {};
  f32x4 aks = {};
  bf16x8 ones;
#pragma unroll
  for (int j = 0; j < 8; j++) ones[j] = (bf16)1.0f;

  for (int chunk = 0; chunk < NSEQ / KSPLIT / 64; ++chunk) {
    const int n0 = sp * (NSEQ / KSPLIT) + chunk * 64;
    __syncthreads();   // previous chunk's reads done before overwrite
    {
      const long g = ((long)(b * NSEQ + n0 + nn)) * NC + h * ND + cg;
      bf16x8 k0 = *(const bf16x8*)(kp + g);
      bf16x8 k1 = *(const bf16x8*)(kp + g + 8);
      bf16x8 v0 = *(const bf16x8*)(vb + g);
      bf16x8 v1 = *(const bf16x8*)(vb + g + 8);
#pragma unroll
      for (int j = 0; j < 8; j++) {
        const int c = cg + j;
        const int idx = c * 64 + (((nn >> 3) ^ (c & 7)) << 3) + (nn & 7);
        kT[idx] = k0[j]; vT[idx] = v0[j];
        const int c2 = cg + 8 + j;
        const int idx2 = c2 * 64 + (((nn >> 3) ^ (c2 & 7)) << 3) + (nn & 7);
        kT[idx2] = k1[j]; vT[idx2] = v1[j];
      }
    }
    __syncthreads();
#pragma unroll
    for (int kk = 0; kk < 2; kk++) {
      const int cA = w * 16 + l16;
      bf16x8 af = *(const bf16x8*)&kT[cA * 64 + (((kk * 4 + q4) ^ (cA & 7)) << 3)];
#pragma unroll
      for (int dt = 0; dt < 4; dt++) {
        const int dR = dt * 16 + l16;
        bf16x8 bf_ = *(const bf16x8*)&vT[dR * 64 + (((kk * 4 + q4) ^ (dR & 7)) << 3)];
        acc[dt] = __builtin_amdgcn_mfma_f32_16x16x32_bf16(af, bf_, acc[dt], 0, 0, 0);
      }
      aks = __builtin_amdgcn_mfma_f32_16x16x32_bf16(af, ones, aks, 0, 0, 0);
    }
  }
  // C/D layout: row(c) = q4*4 + ri, col(d) = l16 (verified mapping)
  const long base = ((long)(sp * NBH + bh)) * 4096;
  const int c0 = w * 16 + q4 * 4;
#pragma unroll
  for (int ri = 0; ri < 4; ri++) {
#pragma unroll
    for (int dt = 0; dt < 4; dt++)
      kv_part[base + (long)(c0 + ri) * 64 + dt * 16 + l16] = acc[dt][ri];
  }
  if (l16 == 0) {
#pragma unroll
    for (int ri = 0; ri < 4; ri++)
      ks_part[(long)(sp * NBH + bh) * 64 + c0 + ri] = aks[ri];
  }
}

__global__ __launch_bounds__(256) void reduce_parts(const float* __restrict__ src,
                                                    float* __restrict__ dst, int n) {
  int i = blockIdx.x * 256 + threadIdx.x;
  if (i < n) {
    float s = 0.f;
    for (int p = 0; p < KSPLIT; ++p) s += src[(long)p * n + i];
    dst[i] = s;
  }
}

// ---------------- z + o = z * q' @ kv ----------------
__global__ __launch_bounds__(256) void z_o(const bf16* __restrict__ qp,
                                           const float* __restrict__ kvm,
                                           const float* __restrict__ ksum,
                                           bf16* __restrict__ ob) {
  __shared__ float kvs[4096];
  __shared__ float kss[64];
  const int bh = blockIdx.x >> 4, chunk = blockIdx.x & 15;
  const int b = bh >> 4, h = bh & 15;
  const int tid = threadIdx.x;
  const int rg = tid >> 2;          // row group 0..63 (4 rows each)
  const int qd = (tid & 3) * 16;    // d-quarter offset

  for (int i = tid; i < 1024; i += 256)
    *(f32x4*)&kvs[i * 4] = *(const f32x4*)&kvm[(long)bh * 4096 + i * 4];
  if (tid < 16)
    *(f32x4*)&kss[tid * 4] = *(const f32x4*)&ksum[(long)bh * 64 + tid * 4];
  __syncthreads();

  const long i0 = (long)b * NSEQ + chunk * 256 + rg * 4;   // first of 4 rows
  const bf16* q0 = qp + i0 * NC + h * ND;

  f32x4 o4[4][4] = {};
  float s[4] = {0.f, 0.f, 0.f, 0.f};
  for (int c8 = 0; c8 < 8; ++c8) {
    bf16x8 q8[4];
#pragma unroll
    for (int r = 0; r < 4; r++) q8[r] = *(const bf16x8*)(q0 + r * NC + c8 * 8);
#pragma unroll
    for (int j = 0; j < 8; j++) {
      const int c = c8 * 8 + j;
      const f32x4* kr = (const f32x4*)&kvs[c * 64 + qd];
      const f32x4 k0 = kr[0], k1 = kr[1], k2 = kr[2], k3 = kr[3];
      const float ksc = kss[c];
#pragma unroll
      for (int r = 0; r < 4; r++) {
        const float qc = (float)q8[r][j];
        o4[r][0] += qc * k0; o4[r][1] += qc * k1;
        o4[r][2] += qc * k2; o4[r][3] += qc * k3;
        s[r] += qc * ksc;
      }
    }
  }
#pragma unroll
  for (int r = 0; r < 4; r++) {
    const float z = 1.0f / (s[r] + EPSF);
    bf16* orow = ob + (i0 + r) * NC + h * ND + qd;
#pragma unroll
    for (int d4 = 0; d4 < 4; d4++) {
      bf16x4 o;
#pragma unroll
      for (int j = 0; j < 4; j++) o[j] = (bf16)(o4[r][d4][j] * z);
      *(bf16x4*)(orow + d4 * 4) = o;
    }
  }
}

// ---------------- launch ----------------
extern "C" void kernel_launch(void* const* d_in, const int* in_sizes, int n_in,
                              void* d_out, int out_size, void* d_ws, size_t ws_size,
                              hipStream_t stream) {
  const float* x = (const float*)d_in[0];
  const float* scale = (const float*)d_in[1];
  const float* pos_enc = (const float*)d_in[2];
  const float* qkv_w = (const float*)d_in[3];
  const float* proj_w = (const float*)d_in[4];
  const float* proj_b = (const float*)d_in[5];
  float* out = (float*)d_out;

  char* ws = (char*)d_ws;
  size_t off = 0;
  auto alloc = [&](size_t bytes) {
    char* p = ws + off;
    off += (bytes + 255) & ~(size_t)255;
    return p;
  };
  bf16* xb = (bf16*)alloc((size_t)NM * NC * 2);          // 64 MB (reused as qp)
  bf16* wqkv = (bf16*)alloc((size_t)3 * NC * NC * 2);    // 6 MB
  bf16* wproj = (bf16*)alloc((size_t)NC * NC * 2);       // 2 MB
  float* inv_sc = (float*)alloc(NC * 4);
  bf16* peb = (bf16*)alloc((size_t)NSEQ * NC * 2);       // 8 MB
  bf16* vb = (bf16*)alloc((size_t)NM * NC * 2);          // 64 MB
  bf16* kp = (bf16*)alloc((size_t)NM * NC * 2);          // 64 MB
  float* ks_part = (float*)alloc((size_t)KSPLIT * NBH * ND * 4);
  float* ksum = (float*)alloc((size_t)NBH * ND * 4);
  float* kvm = (float*)alloc((size_t)NBH * ND * ND * 4); // 2 MB
  bf16* qkb = (bf16*)alloc((size_t)NM * 2048 * 2);       // 128 MB (dead after transform)
  (void)ws_size; (void)n_in; (void)in_sizes; (void)out_size;

  // aliases into the qkb region (qkb is dead after transform_qk):
  bf16* ob = (bf16*)qkb;                                       // 64 MB
  float* kv_part = (float*)((char*)qkb + (size_t)NM * NC * 2); // 16 MB
  bf16* qp = xb;                                               // xb dead after gemm_qkv

  // 1. converts
  cvt_bf16<<<dim3((NM * NC / 4 + 255) / 256), 256, 0, stream>>>(x, xb, NM * NC / 4);
  cvt_bf16<<<dim3((3 * NC * NC / 4 + 255) / 256), 256, 0, stream>>>(qkv_w, wqkv, 3 * NC * NC / 4);
  cvt_bf16<<<dim3((NC * NC / 4 + 255) / 256), 256, 0, stream>>>(proj_w, wproj, NC * NC / 4);
  cvt_bf16<<<dim3((NSEQ * NC / 4 + 255) / 256), 256, 0, stream>>>(pos_enc, peb, NSEQ * NC / 4);
  prep_scale<<<dim3(4), 256, 0, stream>>>(scale, inv_sc);

  // 2. qkv GEMM: (32768 x 1024) @ (3072 x 1024)^T  [256^2 tiles]
  gemm_bt8<0><<<dim3(12, 128), 512, 0, stream>>>(xb, wqkv, NC, qkb, vb, nullptr, nullptr);

  // 3. q/k transform
  transform_qk<<<dim3(NM), 256, 0, stream>>>(qkb, peb, inv_sc, qp, kp);

  // 4. kv / ksum (MFMA)
  kv_mfma<<<dim3(KSPLIT, NBH), 256, 0, stream>>>(kp, vb, kv_part, ks_part);
  reduce_parts<<<dim3((NBH * ND + 255) / 256), 256, 0, stream>>>(ks_part, ksum, NBH * ND);
  reduce_parts<<<dim3((NBH * 4096 + 255) / 256), 256, 0, stream>>>(kv_part, kvm, NBH * 4096);

  // 5. z + o
  z_o<<<dim3(NBH * 16), 256, 0, stream>>>(qp, kvm, ksum, ob);

  // 6. proj GEMM + bias  [256^2 tiles]
  gemm_bt8<1><<<dim3(4, 128), 512, 0, stream>>>(ob, wproj, NC, nullptr, nullptr, out, proj_b);
}

// Round 7
// 727.450 us; speedup vs baseline: 1.2520x; 1.0003x over previous
//
#include <hip/hip_runtime.h>
#include <hip/hip_bf16.h>
#include <cstdint>
#include <cstddef>

// FocusedLinearAttention on MI355X (gfx950).
// R8: GEMM reverted byte-identical to R6 (passed, 240us/qkv). Deep-staging
// vmcnt(8) variant PERMANENTLY DROPPED: 3/3 container hangs (R4,R4b,R7) vs
// 3/3 passes without it (R3,R5,R6) — empirical rule: keep outstanding
// global_load_lds <= 12 per wave. Tail changes kept from R7 (hang-safe,
// standard sync): (a) transform_qk wave-per-row (no LDS/barriers);
// (b) kv_mfma staging packs transposed row-pairs into ds_write_b32.

typedef __bf16 bf16;
typedef __bf16 bf16x4 __attribute__((ext_vector_type(4)));
typedef __bf16 bf16x8 __attribute__((ext_vector_type(8)));
typedef float f32x4 __attribute__((ext_vector_type(4)));
typedef float f32x2 __attribute__((ext_vector_type(2)));

#define NB 8
#define NSEQ 4096
#define NC 1024
#define NH 16
#define ND 64
#define NBH 128      // NB*NH
#define NM 32768     // NB*NSEQ
#define EPSF 1e-6f
#define KSPLIT 8

__device__ __forceinline__ void async16(const void* g, void* l) {
  __builtin_amdgcn_global_load_lds(
      (const __attribute__((address_space(1))) void*)g,
      (__attribute__((address_space(3))) void*)l, 16, 0, 0);
}

__device__ __forceinline__ unsigned pack_bf16(float a, float b) {
  union { bf16 h[2]; unsigned u; } t;
  t.h[0] = (bf16)a; t.h[1] = (bf16)b;
  return t.u;
}

__device__ __forceinline__ unsigned pack2(bf16 a, bf16 b) {
  union { bf16 h[2]; unsigned u; } t;
  t.h[0] = a; t.h[1] = b;
  return t.u;
}

#define BAR() asm volatile("s_barrier" ::: "memory")
#define WAIT_VM(N) asm volatile("s_waitcnt vmcnt(" #N ")" ::: "memory")

// ---------------- fp32 -> bf16 convert ----------------
__global__ __launch_bounds__(256) void cvt_bf16(const float* __restrict__ src,
                                                bf16* __restrict__ dst, int n4) {
  int i = blockIdx.x * 256 + threadIdx.x;
  if (i < n4) {
    f32x4 v = ((const f32x4*)src)[i];
    bf16x4 o;
    o[0] = (bf16)v[0]; o[1] = (bf16)v[1]; o[2] = (bf16)v[2]; o[3] = (bf16)v[3];
    ((bf16x4*)dst)[i] = o;
  }
}

// ---------------- inv softplus(scale) ----------------
__global__ __launch_bounds__(256) void prep_scale(const float* __restrict__ scale,
                                                  float* __restrict__ inv_sc) {
  int c = blockIdx.x * 256 + threadIdx.x;
  if (c < NC) inv_sc[c] = 1.0f / log1pf(expf(scale[c]));
}

// ---------------- 256x256 bf16 MFMA GEMM, C = A @ B^T, 4x1-barrier phases ---
// R6 schedule (harness-verified): A(t+1)@P1/P2 -> buf q, B(t+2)@P3/P4 -> buf p,
// vmcnt(4) once per K-tile at end-P4. Max 12 outstanding global_load_lds.
template <int MODE>
__global__ __launch_bounds__(512, 2) void gemm_bt8(const bf16* __restrict__ A,
                                                   const bf16* __restrict__ Bm, int K,
                                                   bf16* __restrict__ outqk,
                                                   bf16* __restrict__ outv,
                                                   float* __restrict__ outf,
                                                   const float* __restrict__ bias) {
  __shared__ bf16 As[2 * 16384];
  __shared__ bf16 Bs[2 * 16384];

  const int tid = threadIdx.x;
  const int w = tid >> 6, lane = tid & 63;
  const int q4 = lane >> 4, l16 = lane & 15;
  const int l7 = l16 & 7;
  const int wm = (w >> 2) * 128, wn = (w & 3) * 64;   // wave -> 128x64 of C

  // T1: bijective XCD swizzle (nwg % 8 == 0 for all launches here)
  const int gx = gridDim.x;
  const int nwg = gx * gridDim.y;
  const int bid0 = blockIdx.y * gx + blockIdx.x;
  const int cpx = nwg >> 3;
  const int bid = (bid0 & 7) * cpx + (bid0 >> 3);
  const long row0 = (long)(bid / gx) * 256;
  const long col0 = (long)(bid % gx) * 256;

  // Staging geometry: slot s = w*128 + t2*64 + lane; LDS dest linear (slot*16B).
  // T2 swizzle applied on the GLOBAL SOURCE (rule 21): slot (r = s>>3, j = s&7)
  // holds global (row r, colgroup j ^ (r&7)). Involution; reads use same XOR.
  const int s0 = w * 128 + lane;                 // t2=0 slot (t2=1: +64)
  const int ra = s0 >> 3;                        // row within half-tile
  const int cg = ((s0 & 7) ^ (ra & 7)) << 3;     // source col element offset
  const int dl = s0 << 3;                        // LDS element offset within half

  const bf16* Abase = A + (row0 + ra) * (long)K + cg;
  const bf16* Bbase = Bm + (col0 + ra) * (long)K + cg;
  const long rstep = 8 * (long)K;                // +8 rows
  const long hstep = 128 * (long)K;              // +1 half-tile

  auto stA = [&](int buf, int h, int k0) {
    const bf16* g = Abase + h * hstep + k0;
    bf16* l = As + buf * 16384 + h * 8192 + dl;
    async16(g, l);
    async16(g + rstep, l + 512);
  };
  auto stB = [&](int buf, int h, int k0) {
    const bf16* g = Bbase + h * hstep + k0;
    bf16* l = Bs + buf * 16384 + h * 8192 + dl;
    async16(g, l);
    async16(g + rstep, l + 512);
  };

  const int nkt = K >> 6;

  // Prologue: K-tile0 (buf0) fully, K-tile1 B halves (buf1). Order matters
  // for the in-order vmcnt retirement: tile0's 8 loads are oldest.
  stA(0, 0, 0); stA(0, 1, 0);
  stB(0, 0, 0); stB(0, 1, 0);
  {
    const int k1p = (nkt > 1 ? 1 : 0) << 6;
    stB(1, 0, k1p); stB(1, 1, k1p);
  }
  WAIT_VM(4);   // K-tile0 resident; tile1 B stays in flight
  BAR();

  f32x4 acc[8][4] = {};
  bf16x8 af[4][2], bfr[4][2];

  for (int t = 0; t < nkt; ++t) {
    const int p = t & 1, q = p ^ 1;
    const int pb = p * 16384;
    const int k1 = (t + 1 < nkt ? t + 1 : nkt - 1) << 6;
    const int k2 = (t + 2 < nkt ? t + 2 : nkt - 1) << 6;

    // ---- P1: ld A(mhalf0)+B(ni0-1); stage A-h0(t+1)->buf q; MFMA Q(h0,n01) --
#pragma unroll
    for (int mi = 0; mi < 4; mi++) {
      const int rb = (wm + mi * 16 + l16) * 64;
#pragma unroll
      for (int ks = 0; ks < 2; ks++)
        af[mi][ks] = *(const bf16x8*)&As[pb + rb + (((ks * 4 + q4) ^ l7) << 3)];
    }
#pragma unroll
    for (int ni = 0; ni < 2; ni++) {
      const int rb = (wn + ni * 16 + l16) * 64;
#pragma unroll
      for (int ks = 0; ks < 2; ks++)
        bfr[ni][ks] = *(const bf16x8*)&Bs[pb + rb + (((ks * 4 + q4) ^ l7) << 3)];
    }
    stA(q, 0, k1);
    __builtin_amdgcn_s_setprio(1);
#pragma unroll
    for (int mi = 0; mi < 4; mi++)
#pragma unroll
      for (int ni = 0; ni < 2; ni++)
#pragma unroll
        for (int ks = 0; ks < 2; ks++)
          acc[mi][ni] = __builtin_amdgcn_mfma_f32_16x16x32_bf16(
              af[mi][ks], bfr[ni][ks], acc[mi][ni], 0, 0, 0);
    __builtin_amdgcn_s_setprio(0);
    BAR();

    // ---- P2: ld B(ni2-3); stage A-h1(t+1)->buf q; MFMA Q(h0,n23) ----
#pragma unroll
    for (int ni = 2; ni < 4; ni++) {
      const int rb = (wn + ni * 16 + l16) * 64;
#pragma unroll
      for (int ks = 0; ks < 2; ks++)
        bfr[ni][ks] = *(const bf16x8*)&Bs[pb + rb + (((ks * 4 + q4) ^ l7) << 3)];
    }
    stA(q, 1, k1);
    __builtin_amdgcn_s_setprio(1);
#pragma unroll
    for (int mi = 0; mi < 4; mi++)
#pragma unroll
      for (int ni = 2; ni < 4; ni++)
#pragma unroll
        for (int ks = 0; ks < 2; ks++)
          acc[mi][ni] = __builtin_amdgcn_mfma_f32_16x16x32_bf16(
              af[mi][ks], bfr[ni][ks], acc[mi][ni], 0, 0, 0);
    __builtin_amdgcn_s_setprio(0);
    BAR();

    // ---- P3: ld A(mhalf1); stage B-h0(t+2)->buf p (B reads of p consumed
    //      by P2's MFMAs before the P2 end-barrier); MFMA Q(h1,n01) ----
#pragma unroll
    for (int mi = 0; mi < 4; mi++) {
      const int rb = (wm + 64 + mi * 16 + l16) * 64;
#pragma unroll
      for (int ks = 0; ks < 2; ks++)
        af[mi][ks] = *(const bf16x8*)&As[pb + rb + (((ks * 4 + q4) ^ l7) << 3)];
    }
    stB(p, 0, k2);
    __builtin_amdgcn_s_setprio(1);
#pragma unroll
    for (int mi = 0; mi < 4; mi++)
#pragma unroll
      for (int ni = 0; ni < 2; ni++)
#pragma unroll
        for (int ks = 0; ks < 2; ks++)
          acc[4 + mi][ni] = __builtin_amdgcn_mfma_f32_16x16x32_bf16(
              af[mi][ks], bfr[ni][ks], acc[4 + mi][ni], 0, 0, 0);
    __builtin_amdgcn_s_setprio(0);
    BAR();

    // ---- P4: stage B-h1(t+2)->buf p; MFMA Q(h1,n23) from regs; vmcnt(4) ----
    stB(p, 1, k2);
    __builtin_amdgcn_s_setprio(1);
#pragma unroll
    for (int mi = 0; mi < 4; mi++)
#pragma unroll
      for (int ni = 2; ni < 4; ni++)
#pragma unroll
        for (int ks = 0; ks < 2; ks++)
          acc[4 + mi][ni] = __builtin_amdgcn_mfma_f32_16x16x32_bf16(
              af[mi][ks], bfr[ni][ks], acc[4 + mi][ni], 0, 0, 0);
    __builtin_amdgcn_s_setprio(0);
    WAIT_VM(4);   // all of K-tile t+1 resident; only B(t+2) (4 loads) in flight
    BAR();
  }
  WAIT_VM(0);     // drain trailing stages before epilogue/exit

  // ---- packed-pair epilogue (same mapping as verified R2) ----
  const int ev = (l16 & 1) == 0;
#pragma unroll
  for (int mi = 0; mi < 8; mi++) {
    long gr0 = row0 + wm + mi * 16 + q4 * 4;
#pragma unroll
    for (int ni = 0; ni < 4; ni++) {
      long gc = col0 + wn + ni * 16 + l16;
      long cb = gc & ~1L;
      long r2 = gr0 + (ev ? 0 : 2);
      if (MODE == 0) {
        unsigned m01 = pack_bf16(acc[mi][ni][0], acc[mi][ni][1]);
        unsigned m23 = pack_bf16(acc[mi][ni][2], acc[mi][ni][3]);
        unsigned p01 = __shfl_xor(m01, 1);
        unsigned p23 = __shfl_xor(m23, 1);
        unsigned xs = ev ? m01 : p23;
        unsigned ys = ev ? p01 : m23;
        unsigned da = (xs & 0xFFFFu) | (ys << 16);
        unsigned db = (xs >> 16) | (ys & 0xFFFF0000u);
        if (col0 < 2048) {
          *(unsigned*)(outqk + r2 * 2048 + cb) = da;
          *(unsigned*)(outqk + (r2 + 1) * 2048 + cb) = db;
        } else {
          *(unsigned*)(outv + r2 * 1024 + (cb - 2048)) = da;
          *(unsigned*)(outv + (r2 + 1) * 1024 + (cb - 2048)) = db;
        }
      } else {
        float bsum = bias[gc];
        float v0 = acc[mi][ni][0] + bsum, v1 = acc[mi][ni][1] + bsum;
        float v2 = acc[mi][ni][2] + bsum, v3 = acc[mi][ni][3] + bsum;
        float p0 = __shfl_xor(v0, 1), p1 = __shfl_xor(v1, 1);
        float p2 = __shfl_xor(v2, 1), p3 = __shfl_xor(v3, 1);
        f32x2 sa, sb;
        sa[0] = ev ? v0 : p2; sa[1] = ev ? p0 : v2;
        sb[0] = ev ? v1 : p3; sb[1] = ev ? p1 : v3;
        *(f32x2*)(outf + r2 * 1024 + cb) = sa;
        *(f32x2*)(outf + (r2 + 1) * 1024 + cb) = sb;
      }
    }
  }
}

// ---------------- q/k nonlinear transform: one wave per row ----------------
// No LDS, no barriers. Lane handles 16 channels; 6-round shfl_xor reduce.
__global__ __launch_bounds__(256) void transform_qk(const bf16* __restrict__ qkb,
                                                    const bf16* __restrict__ peb,
                                                    const float* __restrict__ inv_sc,
                                                    bf16* __restrict__ qp,
                                                    bf16* __restrict__ kp) {
  const int wave = threadIdx.x >> 6, lane = threadIdx.x & 63;
  const long row = (long)blockIdx.x * 4 + wave;   // 0..NM-1
  const int n = (int)(row & (NSEQ - 1));
  const int c0 = lane * 16;

  bf16x8 qh0 = *(const bf16x8*)(qkb + row * 2048 + c0);
  bf16x8 qh1 = *(const bf16x8*)(qkb + row * 2048 + c0 + 8);
  bf16x8 kh0 = *(const bf16x8*)(qkb + row * 2048 + 1024 + c0);
  bf16x8 kh1 = *(const bf16x8*)(qkb + row * 2048 + 1024 + c0 + 8);
  bf16x8 ph0 = *(const bf16x8*)(peb + (long)n * 1024 + c0);
  bf16x8 ph1 = *(const bf16x8*)(peb + (long)n * 1024 + c0 + 8);
  f32x4 isc[4];
#pragma unroll
  for (int j = 0; j < 4; j++) isc[j] = *(const f32x4*)(inv_sc + c0 + j * 4);

  float q3v[16], k3v[16];
  float s2q = 0.f, s6q = 0.f, s2k = 0.f, s6k = 0.f;
#pragma unroll
  for (int j = 0; j < 16; j++) {
    float qb = (float)(j < 8 ? qh0[j & 7] : qh1[j & 7]);
    float kb = (float)(j < 8 ? kh0[j & 7] : kh1[j & 7]);
    float pe = (float)(j < 8 ? ph0[j & 7] : ph1[j & 7]);
    float is = isc[j >> 2][j & 3];
    float qv = (fmaxf(qb, 0.f) + EPSF) * is;
    float kv = (fmaxf(kb + pe, 0.f) + EPSF) * is;
    float q3 = qv * qv * qv, k3 = kv * kv * kv;
    q3v[j] = q3; k3v[j] = k3;
    s2q += qv * qv; s6q += q3 * q3;
    s2k += kv * kv; s6k += k3 * k3;
  }
#pragma unroll
  for (int off = 32; off > 0; off >>= 1) {
    s2q += __shfl_xor(s2q, off);
    s6q += __shfl_xor(s6q, off);
    s2k += __shfl_xor(s2k, off);
    s6k += __shfl_xor(s6k, off);
  }
  const float fq = sqrtf(s2q / s6q);
  const float fk = sqrtf(s2k / s6k);

  bf16x8 qo0, qo1, ko0, ko1;
#pragma unroll
  for (int j = 0; j < 8; j++) {
    qo0[j] = (bf16)(q3v[j] * fq);     qo1[j] = (bf16)(q3v[8 + j] * fq);
    ko0[j] = (bf16)(k3v[j] * fk);     ko1[j] = (bf16)(k3v[8 + j] * fk);
  }
  *(bf16x8*)(qp + row * 1024 + c0) = qo0;
  *(bf16x8*)(qp + row * 1024 + c0 + 8) = qo1;
  *(bf16x8*)(kp + row * 1024 + c0) = ko0;
  *(bf16x8*)(kp + row * 1024 + c0 + 8) = ko1;
}

// ---------------- kv = k^T v and ksum via MFMA, partial over N/KSPLIT ----------
// Transposed+XOR-swizzled LDS: element (r, n) at r*64 + ((n>>3 ^ (r&7))<<3)
// + (n&7). Staging packs row-pairs (n even, n+1) into one ds_write_b32.
__global__ __launch_bounds__(256) void kv_mfma(const bf16* __restrict__ kp,
                                               const bf16* __restrict__ vb,
                                               float* __restrict__ kv_part,
                                               float* __restrict__ ks_part) {
  __shared__ bf16 kT[64 * 64];
  __shared__ bf16 vT[64 * 64];
  const int sp = blockIdx.x;       // 0..KSPLIT-1
  const int bh = blockIdx.y;       // 0..127
  const int b = bh >> 4, h = bh & 15;
  const int tid = threadIdx.x;
  const int w = tid >> 6, lane = tid & 63;
  const int q4 = lane >> 4, l16 = lane & 15;
  const int nr = (tid >> 3) * 2;   // staging: even row of the pair (0,2,..,62)
  const int cg = (tid & 7) * 8;    // staging: col group (8 cols)
  const int ng = ((nr >> 3) & 7);  // n-group for swizzle (same for nr, nr+1)

  f32x4 acc[4] = {};
  f32x4 aks = {};
  bf16x8 ones;
#pragma unroll
  for (int j = 0; j < 8; j++) ones[j] = (bf16)1.0f;

  for (int chunk = 0; chunk < NSEQ / KSPLIT / 64; ++chunk) {
    const int n0 = sp * (NSEQ / KSPLIT) + chunk * 64;
    __syncthreads();   // previous chunk's reads done before overwrite
    {
      const long g = ((long)(b * NSEQ + n0 + nr)) * NC + h * ND + cg;
      bf16x8 k0 = *(const bf16x8*)(kp + g);
      bf16x8 k1 = *(const bf16x8*)(kp + g + NC);
      bf16x8 v0 = *(const bf16x8*)(vb + g);
      bf16x8 v1 = *(const bf16x8*)(vb + g + NC);
#pragma unroll
      for (int j = 0; j < 8; j++) {
        const int c = cg + j;
        const int idx = c * 64 + ((ng ^ (c & 7)) << 3) + (nr & 7);
        *(unsigned*)&kT[idx] = pack2(k0[j], k1[j]);
        *(unsigned*)&vT[idx] = pack2(v0[j], v1[j]);
      }
    }
    __syncthreads();
#pragma unroll
    for (int kk = 0; kk < 2; kk++) {
      const int cA = w * 16 + l16;
      bf16x8 af = *(const bf16x8*)&kT[cA * 64 + (((kk * 4 + q4) ^ (cA & 7)) << 3)];
#pragma unroll
      for (int dt = 0; dt < 4; dt++) {
        const int dR = dt * 16 + l16;
        bf16x8 bf_ = *(const bf16x8*)&vT[dR * 64 + (((kk * 4 + q4) ^ (dR & 7)) << 3)];
        acc[dt] = __builtin_amdgcn_mfma_f32_16x16x32_bf16(af, bf_, acc[dt], 0, 0, 0);
      }
      aks = __builtin_amdgcn_mfma_f32_16x16x32_bf16(af, ones, aks, 0, 0, 0);
    }
  }
  // C/D layout: row(c) = q4*4 + ri, col(d) = l16 (verified mapping)
  const long base = ((long)(sp * NBH + bh)) * 4096;
  const int c0 = w * 16 + q4 * 4;
#pragma unroll
  for (int ri = 0; ri < 4; ri++) {
#pragma unroll
    for (int dt = 0; dt < 4; dt++)
      kv_part[base + (long)(c0 + ri) * 64 + dt * 16 + l16] = acc[dt][ri];
  }
  if (l16 == 0) {
#pragma unroll
    for (int ri = 0; ri < 4; ri++)
      ks_part[(long)(sp * NBH + bh) * 64 + c0 + ri] = aks[ri];
  }
}

__global__ __launch_bounds__(256) void reduce_parts(const float* __restrict__ src,
                                                    float* __restrict__ dst, int n) {
  int i = blockIdx.x * 256 + threadIdx.x;
  if (i < n) {
    float s = 0.f;
    for (int p = 0; p < KSPLIT; ++p) s += src[(long)p * n + i];
    dst[i] = s;
  }
}

// ---------------- z + o = z * q' @ kv ----------------
__global__ __launch_bounds__(256) void z_o(const bf16* __restrict__ qp,
                                           const float* __restrict__ kvm,
                                           const float* __restrict__ ksum,
                                           bf16* __restrict__ ob) {
  __shared__ float kvs[4096];
  __shared__ float kss[64];
  const int bh = blockIdx.x >> 4, chunk = blockIdx.x & 15;
  const int b = bh >> 4, h = bh & 15;
  const int tid = threadIdx.x;
  const int rg = tid >> 2;          // row group 0..63 (4 rows each)
  const int qd = (tid & 3) * 16;    // d-quarter offset

  for (int i = tid; i < 1024; i += 256)
    *(f32x4*)&kvs[i * 4] = *(const f32x4*)&kvm[(long)bh * 4096 + i * 4];
  if (tid < 16)
    *(f32x4*)&kss[tid * 4] = *(const f32x4*)&ksum[(long)bh * 64 + tid * 4];
  __syncthreads();

  const long i0 = (long)b * NSEQ + chunk * 256 + rg * 4;   // first of 4 rows
  const bf16* q0 = qp + i0 * NC + h * ND;

  f32x4 o4[4][4] = {};
  float s[4] = {0.f, 0.f, 0.f, 0.f};
  for (int c8 = 0; c8 < 8; ++c8) {
    bf16x8 q8[4];
#pragma unroll
    for (int r = 0; r < 4; r++) q8[r] = *(const bf16x8*)(q0 + r * NC + c8 * 8);
#pragma unroll
    for (int j = 0; j < 8; j++) {
      const int c = c8 * 8 + j;
      const f32x4* kr = (const f32x4*)&kvs[c * 64 + qd];
      const f32x4 k0 = kr[0], k1 = kr[1], k2 = kr[2], k3 = kr[3];
      const float ksc = kss[c];
#pragma unroll
      for (int r = 0; r < 4; r++) {
        const float qc = (float)q8[r][j];
        o4[r][0] += qc * k0; o4[r][1] += qc * k1;
        o4[r][2] += qc * k2; o4[r][3] += qc * k3;
        s[r] += qc * ksc;
      }
    }
  }
#pragma unroll
  for (int r = 0; r < 4; r++) {
    const float z = 1.0f / (s[r] + EPSF);
    bf16* orow = ob + (i0 + r) * NC + h * ND + qd;
#pragma unroll
    for (int d4 = 0; d4 < 4; d4++) {
      bf16x4 o;
#pragma unroll
      for (int j = 0; j < 4; j++) o[j] = (bf16)(o4[r][d4][j] * z);
      *(bf16x4*)(orow + d4 * 4) = o;
    }
  }
}

// ---------------- launch ----------------
extern "C" void kernel_launch(void* const* d_in, const int* in_sizes, int n_in,
                              void* d_out, int out_size, void* d_ws, size_t ws_size,
                              hipStream_t stream) {
  const float* x = (const float*)d_in[0];
  const float* scale = (const float*)d_in[1];
  const float* pos_enc = (const float*)d_in[2];
  const float* qkv_w = (const float*)d_in[3];
  const float* proj_w = (const float*)d_in[4];
  const float* proj_b = (const float*)d_in[5];
  float* out = (float*)d_out;

  char* ws = (char*)d_ws;
  size_t off = 0;
  auto alloc = [&](size_t bytes) {
    char* p = ws + off;
    off += (bytes + 255) & ~(size_t)255;
    return p;
  };
  bf16* xb = (bf16*)alloc((size_t)NM * NC * 2);          // 64 MB (reused as qp)
  bf16* wqkv = (bf16*)alloc((size_t)3 * NC * NC * 2);    // 6 MB
  bf16* wproj = (bf16*)alloc((size_t)NC * NC * 2);       // 2 MB
  float* inv_sc = (float*)alloc(NC * 4);
  bf16* peb = (bf16*)alloc((size_t)NSEQ * NC * 2);       // 8 MB
  bf16* vb = (bf16*)alloc((size_t)NM * NC * 2);          // 64 MB
  bf16* kp = (bf16*)alloc((size_t)NM * NC * 2);          // 64 MB
  float* ks_part = (float*)alloc((size_t)KSPLIT * NBH * ND * 4);
  float* ksum = (float*)alloc((size_t)NBH * ND * 4);
  float* kvm = (float*)alloc((size_t)NBH * ND * ND * 4); // 2 MB
  bf16* qkb = (bf16*)alloc((size_t)NM * 2048 * 2);       // 128 MB (dead after transform)
  (void)ws_size; (void)n_in; (void)in_sizes; (void)out_size;

  // aliases into the qkb region (qkb is dead after transform_qk):
  bf16* ob = (bf16*)qkb;                                       // 64 MB
  float* kv_part = (float*)((char*)qkb + (size_t)NM * NC * 2); // 16 MB
  bf16* qp = xb;                                               // xb dead after gemm_qkv

  // 1. converts
  cvt_bf16<<<dim3((NM * NC / 4 + 255) / 256), 256, 0, stream>>>(x, xb, NM * NC / 4);
  cvt_bf16<<<dim3((3 * NC * NC / 4 + 255) / 256), 256, 0, stream>>>(qkv_w, wqkv, 3 * NC * NC / 4);
  cvt_bf16<<<dim3((NC * NC / 4 + 255) / 256), 256, 0, stream>>>(proj_w, wproj, NC * NC / 4);
  cvt_bf16<<<dim3((NSEQ * NC / 4 + 255) / 256), 256, 0, stream>>>(pos_enc, peb, NSEQ * NC / 4);
  prep_scale<<<dim3(4), 256, 0, stream>>>(scale, inv_sc);

  // 2. qkv GEMM: (32768 x 1024) @ (3072 x 1024)^T  [256^2 tiles]
  gemm_bt8<0><<<dim3(12, 128), 512, 0, stream>>>(xb, wqkv, NC, qkb, vb, nullptr, nullptr);

  // 3. q/k transform (wave-per-row)
  transform_qk<<<dim3(NM / 4), 256, 0, stream>>>(qkb, peb, inv_sc, qp, kp);

  // 4. kv / ksum (MFMA)
  kv_mfma<<<dim3(KSPLIT, NBH), 256, 0, stream>>>(kp, vb, kv_part, ks_part);
  reduce_parts<<<dim3((NBH * ND + 255) / 256), 256, 0, stream>>>(ks_part, ksum, NBH * ND);
  reduce_parts<<<dim3((NBH * 4096 + 255) / 256), 256, 0, stream>>>(kv_part, kvm, NBH * 4096);

  // 5. z + o
  z_o<<<dim3(NBH * 16), 256, 0, stream>>>(qp, kvm, ksum, ob);

  // 6. proj GEMM + bias  [256^2 tiles]
  gemm_bt8<1><<<dim3(4, 128), 512, 0, stream>>>(ob, wproj, NC, nullptr, nullptr, out, proj_b);
}

// Round 8
// 706.565 us; speedup vs baseline: 1.2890x; 1.0296x over previous
//
#include <hip/hip_runtime.h>
#include <hip/hip_bf16.h>
#include <cstdint>
#include <cstddef>

// FocusedLinearAttention on MI355X (gfx950).
// R9: GEMM K-tile phases merged 4->1: all 24 frag reads issued up front
// (separate register sets), compiler software-pipelines reads vs 64 MFMAs
// with per-operand lgkmcnt; TWO barriers per K-tile instead of four.
// Staging placement / vmcnt(4) / in-flight profile (max 12) byte-identical
// to the 3x-passing R6 schedule. Non-GEMM kernels frozen (= R8).

typedef __bf16 bf16;
typedef __bf16 bf16x4 __attribute__((ext_vector_type(4)));
typedef __bf16 bf16x8 __attribute__((ext_vector_type(8)));
typedef float f32x4 __attribute__((ext_vector_type(4)));
typedef float f32x2 __attribute__((ext_vector_type(2)));

#define NB 8
#define NSEQ 4096
#define NC 1024
#define NH 16
#define ND 64
#define NBH 128      // NB*NH
#define NM 32768     // NB*NSEQ
#define EPSF 1e-6f
#define KSPLIT 8

__device__ __forceinline__ void async16(const void* g, void* l) {
  __builtin_amdgcn_global_load_lds(
      (const __attribute__((address_space(1))) void*)g,
      (__attribute__((address_space(3))) void*)l, 16, 0, 0);
}

__device__ __forceinline__ unsigned pack_bf16(float a, float b) {
  union { bf16 h[2]; unsigned u; } t;
  t.h[0] = (bf16)a; t.h[1] = (bf16)b;
  return t.u;
}

__device__ __forceinline__ unsigned pack2(bf16 a, bf16 b) {
  union { bf16 h[2]; unsigned u; } t;
  t.h[0] = a; t.h[1] = b;
  return t.u;
}

#define BAR() asm volatile("s_barrier" ::: "memory")
#define WAIT_VM(N) asm volatile("s_waitcnt vmcnt(" #N ")" ::: "memory")

// ---------------- fp32 -> bf16 convert ----------------
__global__ __launch_bounds__(256) void cvt_bf16(const float* __restrict__ src,
                                                bf16* __restrict__ dst, int n4) {
  int i = blockIdx.x * 256 + threadIdx.x;
  if (i < n4) {
    f32x4 v = ((const f32x4*)src)[i];
    bf16x4 o;
    o[0] = (bf16)v[0]; o[1] = (bf16)v[1]; o[2] = (bf16)v[2]; o[3] = (bf16)v[3];
    ((bf16x4*)dst)[i] = o;
  }
}

// ---------------- inv softplus(scale) ----------------
__global__ __launch_bounds__(256) void prep_scale(const float* __restrict__ scale,
                                                  float* __restrict__ inv_sc) {
  int c = blockIdx.x * 256 + threadIdx.x;
  if (c < NC) inv_sc[c] = 1.0f / log1pf(expf(scale[c]));
}

// ---------------- 256x256 bf16 MFMA GEMM, C = A @ B^T ----------------
// Merged K-tile body, 2 barriers/K-tile. Stage placement = R6 (verified):
// A(t+1) -> buf q at tile top; B(t+2) -> buf p after the read-sealing
// barrier; vmcnt(4) retires B(t+1)+A(t+1) leaving B(t+2) in flight.
template <int MODE>
__global__ __launch_bounds__(512, 2) void gemm_bt8(const bf16* __restrict__ A,
                                                   const bf16* __restrict__ Bm, int K,
                                                   bf16* __restrict__ outqk,
                                                   bf16* __restrict__ outv,
                                                   float* __restrict__ outf,
                                                   const float* __restrict__ bias) {
  __shared__ bf16 As[2 * 16384];
  __shared__ bf16 Bs[2 * 16384];

  const int tid = threadIdx.x;
  const int w = tid >> 6, lane = tid & 63;
  const int q4 = lane >> 4, l16 = lane & 15;
  const int l7 = l16 & 7;
  const int wm = (w >> 2) * 128, wn = (w & 3) * 64;   // wave -> 128x64 of C

  // T1: bijective XCD swizzle (nwg % 8 == 0 for all launches here)
  const int gx = gridDim.x;
  const int nwg = gx * gridDim.y;
  const int bid0 = blockIdx.y * gx + blockIdx.x;
  const int cpx = nwg >> 3;
  const int bid = (bid0 & 7) * cpx + (bid0 >> 3);
  const long row0 = (long)(bid / gx) * 256;
  const long col0 = (long)(bid % gx) * 256;

  // Staging geometry: slot s = w*128 + t2*64 + lane; LDS dest linear (slot*16B).
  // T2 swizzle applied on the GLOBAL SOURCE (rule 21): slot (r = s>>3, j = s&7)
  // holds global (row r, colgroup j ^ (r&7)). Involution; reads use same XOR.
  const int s0 = w * 128 + lane;                 // t2=0 slot (t2=1: +64)
  const int ra = s0 >> 3;                        // row within half-tile
  const int cg = ((s0 & 7) ^ (ra & 7)) << 3;     // source col element offset
  const int dl = s0 << 3;                        // LDS element offset within half

  const bf16* Abase = A + (row0 + ra) * (long)K + cg;
  const bf16* Bbase = Bm + (col0 + ra) * (long)K + cg;
  const long rstep = 8 * (long)K;                // +8 rows
  const long hstep = 128 * (long)K;              // +1 half-tile

  auto stA = [&](int buf, int h, int k0) {
    const bf16* g = Abase + h * hstep + k0;
    bf16* l = As + buf * 16384 + h * 8192 + dl;
    async16(g, l);
    async16(g + rstep, l + 512);
  };
  auto stB = [&](int buf, int h, int k0) {
    const bf16* g = Bbase + h * hstep + k0;
    bf16* l = Bs + buf * 16384 + h * 8192 + dl;
    async16(g, l);
    async16(g + rstep, l + 512);
  };

  const int nkt = K >> 6;

  // Prologue: K-tile0 (buf0) fully, K-tile1 B halves (buf1). Order matters
  // for the in-order vmcnt retirement: tile0's 8 loads are oldest.
  stA(0, 0, 0); stA(0, 1, 0);
  stB(0, 0, 0); stB(0, 1, 0);
  {
    const int k1p = (nkt > 1 ? 1 : 0) << 6;
    stB(1, 0, k1p); stB(1, 1, k1p);
  }
  WAIT_VM(4);   // K-tile0 resident; tile1 B stays in flight
  BAR();

  f32x4 acc[8][4] = {};

  for (int t = 0; t < nkt; ++t) {
    const int p = t & 1, q = p ^ 1;
    const int pb = p * 16384;
    const int k1 = (t + 1 < nkt ? t + 1 : nkt - 1) << 6;
    const int k2 = (t + 2 < nkt ? t + 2 : nkt - 1) << 6;

    // ---- all fragment reads of buf p (compiler pipelines vs MFMAs) ----
    bf16x8 af[4][2], ag[4][2], bfr[4][2];
#pragma unroll
    for (int mi = 0; mi < 4; mi++) {
      const int rb0 = (wm + mi * 16 + l16) * 64;
      const int rb1 = (wm + 64 + mi * 16 + l16) * 64;
#pragma unroll
      for (int ks = 0; ks < 2; ks++) {
        af[mi][ks] = *(const bf16x8*)&As[pb + rb0 + (((ks * 4 + q4) ^ l7) << 3)];
        ag[mi][ks] = *(const bf16x8*)&As[pb + rb1 + (((ks * 4 + q4) ^ l7) << 3)];
      }
    }
#pragma unroll
    for (int ni = 0; ni < 4; ni++) {
      const int rb = (wn + ni * 16 + l16) * 64;
#pragma unroll
      for (int ks = 0; ks < 2; ks++)
        bfr[ni][ks] = *(const bf16x8*)&Bs[pb + rb + (((ks * 4 + q4) ^ l7) << 3)];
    }

    // stage A(t+1) -> buf q (its last readers finished before the barrier
    // that ended iteration t-1)
    stA(q, 0, k1); stA(q, 1, k1);

    __builtin_amdgcn_s_setprio(1);
#pragma unroll
    for (int mi = 0; mi < 4; mi++)
#pragma unroll
      for (int ni = 0; ni < 4; ni++)
#pragma unroll
        for (int ks = 0; ks < 2; ks++)
          acc[mi][ni] = __builtin_amdgcn_mfma_f32_16x16x32_bf16(
              af[mi][ks], bfr[ni][ks], acc[mi][ni], 0, 0, 0);
#pragma unroll
    for (int mi = 0; mi < 4; mi++)
#pragma unroll
      for (int ni = 0; ni < 4; ni++)
#pragma unroll
        for (int ks = 0; ks < 2; ks++)
          acc[4 + mi][ni] = __builtin_amdgcn_mfma_f32_16x16x32_bf16(
              ag[mi][ks], bfr[ni][ks], acc[4 + mi][ni], 0, 0, 0);
    __builtin_amdgcn_s_setprio(0);

    // A wave reaching this barrier has completed ALL its ds_reads of buf p
    // (its MFMAs consumed them) -> after the barrier, buf p is safe to write.
    BAR();
    stB(p, 0, k2); stB(p, 1, k2);
    WAIT_VM(4);   // retires B(t+1)+A(t+1); only B(t+2) (4 loads) in flight
    BAR();        // buf q (= tile t+1) resident for next iteration
  }
  WAIT_VM(0);     // drain trailing stages before epilogue/exit

  // ---- packed-pair epilogue (same mapping as verified R2) ----
  const int ev = (l16 & 1) == 0;
#pragma unroll
  for (int mi = 0; mi < 8; mi++) {
    long gr0 = row0 + wm + mi * 16 + q4 * 4;
#pragma unroll
    for (int ni = 0; ni < 4; ni++) {
      long gc = col0 + wn + ni * 16 + l16;
      long cb = gc & ~1L;
      long r2 = gr0 + (ev ? 0 : 2);
      if (MODE == 0) {
        unsigned m01 = pack_bf16(acc[mi][ni][0], acc[mi][ni][1]);
        unsigned m23 = pack_bf16(acc[mi][ni][2], acc[mi][ni][3]);
        unsigned p01 = __shfl_xor(m01, 1);
        unsigned p23 = __shfl_xor(m23, 1);
        unsigned xs = ev ? m01 : p23;
        unsigned ys = ev ? p01 : m23;
        unsigned da = (xs & 0xFFFFu) | (ys << 16);
        unsigned db = (xs >> 16) | (ys & 0xFFFF0000u);
        if (col0 < 2048) {
          *(unsigned*)(outqk + r2 * 2048 + cb) = da;
          *(unsigned*)(outqk + (r2 + 1) * 2048 + cb) = db;
        } else {
          *(unsigned*)(outv + r2 * 1024 + (cb - 2048)) = da;
          *(unsigned*)(outv + (r2 + 1) * 1024 + (cb - 2048)) = db;
        }
      } else {
        float bsum = bias[gc];
        float v0 = acc[mi][ni][0] + bsum, v1 = acc[mi][ni][1] + bsum;
        float v2 = acc[mi][ni][2] + bsum, v3 = acc[mi][ni][3] + bsum;
        float p0 = __shfl_xor(v0, 1), p1 = __shfl_xor(v1, 1);
        float p2 = __shfl_xor(v2, 1), p3 = __shfl_xor(v3, 1);
        f32x2 sa, sb;
        sa[0] = ev ? v0 : p2; sa[1] = ev ? p0 : v2;
        sb[0] = ev ? v1 : p3; sb[1] = ev ? p1 : v3;
        *(f32x2*)(outf + r2 * 1024 + cb) = sa;
        *(f32x2*)(outf + (r2 + 1) * 1024 + cb) = sb;
      }
    }
  }
}

// ---------------- q/k nonlinear transform: one wave per row ----------------
__global__ __launch_bounds__(256) void transform_qk(const bf16* __restrict__ qkb,
                                                    const bf16* __restrict__ peb,
                                                    const float* __restrict__ inv_sc,
                                                    bf16* __restrict__ qp,
                                                    bf16* __restrict__ kp) {
  const int wave = threadIdx.x >> 6, lane = threadIdx.x & 63;
  const long row = (long)blockIdx.x * 4 + wave;   // 0..NM-1
  const int n = (int)(row & (NSEQ - 1));
  const int c0 = lane * 16;

  bf16x8 qh0 = *(const bf16x8*)(qkb + row * 2048 + c0);
  bf16x8 qh1 = *(const bf16x8*)(qkb + row * 2048 + c0 + 8);
  bf16x8 kh0 = *(const bf16x8*)(qkb + row * 2048 + 1024 + c0);
  bf16x8 kh1 = *(const bf16x8*)(qkb + row * 2048 + 1024 + c0 + 8);
  bf16x8 ph0 = *(const bf16x8*)(peb + (long)n * 1024 + c0);
  bf16x8 ph1 = *(const bf16x8*)(peb + (long)n * 1024 + c0 + 8);
  f32x4 isc[4];
#pragma unroll
  for (int j = 0; j < 4; j++) isc[j] = *(const f32x4*)(inv_sc + c0 + j * 4);

  float q3v[16], k3v[16];
  float s2q = 0.f, s6q = 0.f, s2k = 0.f, s6k = 0.f;
#pragma unroll
  for (int j = 0; j < 16; j++) {
    float qb = (float)(j < 8 ? qh0[j & 7] : qh1[j & 7]);
    float kb = (float)(j < 8 ? kh0[j & 7] : kh1[j & 7]);
    float pe = (float)(j < 8 ? ph0[j & 7] : ph1[j & 7]);
    float is = isc[j >> 2][j & 3];
    float qv = (fmaxf(qb, 0.f) + EPSF) * is;
    float kv = (fmaxf(kb + pe, 0.f) + EPSF) * is;
    float q3 = qv * qv * qv, k3 = kv * kv * kv;
    q3v[j] = q3; k3v[j] = k3;
    s2q += qv * qv; s6q += q3 * q3;
    s2k += kv * kv; s6k += k3 * k3;
  }
#pragma unroll
  for (int off = 32; off > 0; off >>= 1) {
    s2q += __shfl_xor(s2q, off);
    s6q += __shfl_xor(s6q, off);
    s2k += __shfl_xor(s2k, off);
    s6k += __shfl_xor(s6k, off);
  }
  const float fq = sqrtf(s2q / s6q);
  const float fk = sqrtf(s2k / s6k);

  bf16x8 qo0, qo1, ko0, ko1;
#pragma unroll
  for (int j = 0; j < 8; j++) {
    qo0[j] = (bf16)(q3v[j] * fq);     qo1[j] = (bf16)(q3v[8 + j] * fq);
    ko0[j] = (bf16)(k3v[j] * fk);     ko1[j] = (bf16)(k3v[8 + j] * fk);
  }
  *(bf16x8*)(qp + row * 1024 + c0) = qo0;
  *(bf16x8*)(qp + row * 1024 + c0 + 8) = qo1;
  *(bf16x8*)(kp + row * 1024 + c0) = ko0;
  *(bf16x8*)(kp + row * 1024 + c0 + 8) = ko1;
}

// ---------------- kv = k^T v and ksum via MFMA, partial over N/KSPLIT ----------
__global__ __launch_bounds__(256) void kv_mfma(const bf16* __restrict__ kp,
                                               const bf16* __restrict__ vb,
                                               float* __restrict__ kv_part,
                                               float* __restrict__ ks_part) {
  __shared__ bf16 kT[64 * 64];
  __shared__ bf16 vT[64 * 64];
  const int sp = blockIdx.x;       // 0..KSPLIT-1
  const int bh = blockIdx.y;       // 0..127
  const int b = bh >> 4, h = bh & 15;
  const int tid = threadIdx.x;
  const int w = tid >> 6, lane = tid & 63;
  const int q4 = lane >> 4, l16 = lane & 15;
  const int nr = (tid >> 3) * 2;   // staging: even row of the pair (0,2,..,62)
  const int cg = (tid & 7) * 8;    // staging: col group (8 cols)
  const int ng = ((nr >> 3) & 7);  // n-group for swizzle (same for nr, nr+1)

  f32x4 acc[4] = {};
  f32x4 aks = {};
  bf16x8 ones;
#pragma unroll
  for (int j = 0; j < 8; j++) ones[j] = (bf16)1.0f;

  for (int chunk = 0; chunk < NSEQ / KSPLIT / 64; ++chunk) {
    const int n0 = sp * (NSEQ / KSPLIT) + chunk * 64;
    __syncthreads();   // previous chunk's reads done before overwrite
    {
      const long g = ((long)(b * NSEQ + n0 + nr)) * NC + h * ND + cg;
      bf16x8 k0 = *(const bf16x8*)(kp + g);
      bf16x8 k1 = *(const bf16x8*)(kp + g + NC);
      bf16x8 v0 = *(const bf16x8*)(vb + g);
      bf16x8 v1 = *(const bf16x8*)(vb + g + NC);
#pragma unroll
      for (int j = 0; j < 8; j++) {
        const int c = cg + j;
        const int idx = c * 64 + ((ng ^ (c & 7)) << 3) + (nr & 7);
        *(unsigned*)&kT[idx] = pack2(k0[j], k1[j]);
        *(unsigned*)&vT[idx] = pack2(v0[j], v1[j]);
      }
    }
    __syncthreads();
#pragma unroll
    for (int kk = 0; kk < 2; kk++) {
      const int cA = w * 16 + l16;
      bf16x8 af = *(const bf16x8*)&kT[cA * 64 + (((kk * 4 + q4) ^ (cA & 7)) << 3)];
#pragma unroll
      for (int dt = 0; dt < 4; dt++) {
        const int dR = dt * 16 + l16;
        bf16x8 bf_ = *(const bf16x8*)&vT[dR * 64 + (((kk * 4 + q4) ^ (dR & 7)) << 3)];
        acc[dt] = __builtin_amdgcn_mfma_f32_16x16x32_bf16(af, bf_, acc[dt], 0, 0, 0);
      }
      aks = __builtin_amdgcn_mfma_f32_16x16x32_bf16(af, ones, aks, 0, 0, 0);
    }
  }
  // C/D layout: row(c) = q4*4 + ri, col(d) = l16 (verified mapping)
  const long base = ((long)(sp * NBH + bh)) * 4096;
  const int c0 = w * 16 + q4 * 4;
#pragma unroll
  for (int ri = 0; ri < 4; ri++) {
#pragma unroll
    for (int dt = 0; dt < 4; dt++)
      kv_part[base + (long)(c0 + ri) * 64 + dt * 16 + l16] = acc[dt][ri];
  }
  if (l16 == 0) {
#pragma unroll
    for (int ri = 0; ri < 4; ri++)
      ks_part[(long)(sp * NBH + bh) * 64 + c0 + ri] = aks[ri];
  }
}

__global__ __launch_bounds__(256) void reduce_parts(const float* __restrict__ src,
                                                    float* __restrict__ dst, int n) {
  int i = blockIdx.x * 256 + threadIdx.x;
  if (i < n) {
    float s = 0.f;
    for (int p = 0; p < KSPLIT; ++p) s += src[(long)p * n + i];
    dst[i] = s;
  }
}

// ---------------- z + o = z * q' @ kv ----------------
__global__ __launch_bounds__(256) void z_o(const bf16* __restrict__ qp,
                                           const float* __restrict__ kvm,
                                           const float* __restrict__ ksum,
                                           bf16* __restrict__ ob) {
  __shared__ float kvs[4096];
  __shared__ float kss[64];
  const int bh = blockIdx.x >> 4, chunk = blockIdx.x & 15;
  const int b = bh >> 4, h = bh & 15;
  const int tid = threadIdx.x;
  const int rg = tid >> 2;          // row group 0..63 (4 rows each)
  const int qd = (tid & 3) * 16;    // d-quarter offset

  for (int i = tid; i < 1024; i += 256)
    *(f32x4*)&kvs[i * 4] = *(const f32x4*)&kvm[(long)bh * 4096 + i * 4];
  if (tid < 16)
    *(f32x4*)&kss[tid * 4] = *(const f32x4*)&ksum[(long)bh * 64 + tid * 4];
  __syncthreads();

  const long i0 = (long)b * NSEQ + chunk * 256 + rg * 4;   // first of 4 rows
  const bf16* q0 = qp + i0 * NC + h * ND;

  f32x4 o4[4][4] = {};
  float s[4] = {0.f, 0.f, 0.f, 0.f};
  for (int c8 = 0; c8 < 8; ++c8) {
    bf16x8 q8[4];
#pragma unroll
    for (int r = 0; r < 4; r++) q8[r] = *(const bf16x8*)(q0 + r * NC + c8 * 8);
#pragma unroll
    for (int j = 0; j < 8; j++) {
      const int c = c8 * 8 + j;
      const f32x4* kr = (const f32x4*)&kvs[c * 64 + qd];
      const f32x4 k0 = kr[0], k1 = kr[1], k2 = kr[2], k3 = kr[3];
      const float ksc = kss[c];
#pragma unroll
      for (int r = 0; r < 4; r++) {
        const float qc = (float)q8[r][j];
        o4[r][0] += qc * k0; o4[r][1] += qc * k1;
        o4[r][2] += qc * k2; o4[r][3] += qc * k3;
        s[r] += qc * ksc;
      }
    }
  }
#pragma unroll
  for (int r = 0; r < 4; r++) {
    const float z = 1.0f / (s[r] + EPSF);
    bf16* orow = ob + (i0 + r) * NC + h * ND + qd;
#pragma unroll
    for (int d4 = 0; d4 < 4; d4++) {
      bf16x4 o;
#pragma unroll
      for (int j = 0; j < 4; j++) o[j] = (bf16)(o4[r][d4][j] * z);
      *(bf16x4*)(orow + d4 * 4) = o;
    }
  }
}

// ---------------- launch ----------------
extern "C" void kernel_launch(void* const* d_in, const int* in_sizes, int n_in,
                              void* d_out, int out_size, void* d_ws, size_t ws_size,
                              hipStream_t stream) {
  const float* x = (const float*)d_in[0];
  const float* scale = (const float*)d_in[1];
  const float* pos_enc = (const float*)d_in[2];
  const float* qkv_w = (const float*)d_in[3];
  const float* proj_w = (const float*)d_in[4];
  const float* proj_b = (const float*)d_in[5];
  float* out = (float*)d_out;

  char* ws = (char*)d_ws;
  size_t off = 0;
  auto alloc = [&](size_t bytes) {
    char* p = ws + off;
    off += (bytes + 255) & ~(size_t)255;
    return p;
  };
  bf16* xb = (bf16*)alloc((size_t)NM * NC * 2);          // 64 MB (reused as qp)
  bf16* wqkv = (bf16*)alloc((size_t)3 * NC * NC * 2);    // 6 MB
  bf16* wproj = (bf16*)alloc((size_t)NC * NC * 2);       // 2 MB
  float* inv_sc = (float*)alloc(NC * 4);
  bf16* peb = (bf16*)alloc((size_t)NSEQ * NC * 2);       // 8 MB
  bf16* vb = (bf16*)alloc((size_t)NM * NC * 2);          // 64 MB
  bf16* kp = (bf16*)alloc((size_t)NM * NC * 2);          // 64 MB
  float* ks_part = (float*)alloc((size_t)KSPLIT * NBH * ND * 4);
  float* ksum = (float*)alloc((size_t)NBH * ND * 4);
  float* kvm = (float*)alloc((size_t)NBH * ND * ND * 4); // 2 MB
  bf16* qkb = (bf16*)alloc((size_t)NM * 2048 * 2);       // 128 MB (dead after transform)
  (void)ws_size; (void)n_in; (void)in_sizes; (void)out_size;

  // aliases into the qkb region (qkb is dead after transform_qk):
  bf16* ob = (bf16*)qkb;                                       // 64 MB
  float* kv_part = (float*)((char*)qkb + (size_t)NM * NC * 2); // 16 MB
  bf16* qp = xb;                                               // xb dead after gemm_qkv

  // 1. converts
  cvt_bf16<<<dim3((NM * NC / 4 + 255) / 256), 256, 0, stream>>>(x, xb, NM * NC / 4);
  cvt_bf16<<<dim3((3 * NC * NC / 4 + 255) / 256), 256, 0, stream>>>(qkv_w, wqkv, 3 * NC * NC / 4);
  cvt_bf16<<<dim3((NC * NC / 4 + 255) / 256), 256, 0, stream>>>(proj_w, wproj, NC * NC / 4);
  cvt_bf16<<<dim3((NSEQ * NC / 4 + 255) / 256), 256, 0, stream>>>(pos_enc, peb, NSEQ * NC / 4);
  prep_scale<<<dim3(4), 256, 0, stream>>>(scale, inv_sc);

  // 2. qkv GEMM: (32768 x 1024) @ (3072 x 1024)^T  [256^2 tiles]
  gemm_bt8<0><<<dim3(12, 128), 512, 0, stream>>>(xb, wqkv, NC, qkb, vb, nullptr, nullptr);

  // 3. q/k transform (wave-per-row)
  transform_qk<<<dim3(NM / 4), 256, 0, stream>>>(qkb, peb, inv_sc, qp, kp);

  // 4. kv / ksum (MFMA)
  kv_mfma<<<dim3(KSPLIT, NBH), 256, 0, stream>>>(kp, vb, kv_part, ks_part);
  reduce_parts<<<dim3((NBH * ND + 255) / 256), 256, 0, stream>>>(ks_part, ksum, NBH * ND);
  reduce_parts<<<dim3((NBH * 4096 + 255) / 256), 256, 0, stream>>>(kv_part, kvm, NBH * 4096);

  // 5. z + o
  z_o<<<dim3(NBH * 16), 256, 0, stream>>>(qp, kvm, ksum, ob);

  // 6. proj GEMM + bias  [256^2 tiles]
  gemm_bt8<1><<<dim3(4, 128), 512, 0, stream>>>(ob, wproj, NC, nullptr, nullptr, out, proj_b);
}